// Round 1
// baseline (341.218 us; speedup 1.0000x reference)
//
#include <hip/hip_runtime.h>
#include <stdint.h>

#define BATCH 16
#define CH    256
#define CI    128
#define NSP   4096
#define EPSV  1e-5f

typedef unsigned short u16;
typedef __attribute__((ext_vector_type(4))) float f32x4;
typedef __attribute__((ext_vector_type(8))) short bf16x8;

__device__ __forceinline__ u16 f2b(float f) {
  uint32_t u = __float_as_uint(f);
  uint32_t r = u + 0x7FFFu + ((u >> 16) & 1u);   // round-to-nearest-even
  return (u16)(r >> 16);
}

// ---------------- kernel 1: bf16 convert (row-major + transposed) + row sums
// grid (NSP/64, CH/64, BATCH), block 256
__global__ __launch_bounds__(256) void k_prep(const float* __restrict__ x,
    u16* __restrict__ xb, u16* __restrict__ xt, float* __restrict__ svec) {
  __shared__ float tile[64*64];
  const int b = blockIdx.z, c0 = blockIdx.y*64, n0 = blockIdx.x*64;
  const int t = threadIdx.x;
  const int lane16 = t & 15;
  const int grp = t >> 4;              // 0..15
  const float* xp = x + ((size_t)b*CH + c0)*NSP + n0;
  u16* xbp = xb + ((size_t)b*CH + c0)*NSP + n0;
  #pragma unroll
  for (int p = 0; p < 4; ++p) {
    int cl = grp + p*16;               // row within tile, 0..63
    int nl = lane16*4;
    float4 v = *(const float4*)(xp + (size_t)cl*NSP + nl);
    // row-sum partial (16 lanes per row are consecutive)
    float ps = v.x + v.y + v.z + v.w;
    #pragma unroll
    for (int o = 1; o < 16; o <<= 1) ps += __shfl_xor(ps, o, 64);
    if (lane16 == 0) atomicAdd(&svec[b*CH + c0 + cl], ps);
    // bf16 row-major store
    ushort4 bv; bv.x=f2b(v.x); bv.y=f2b(v.y); bv.z=f2b(v.z); bv.w=f2b(v.w);
    *(ushort4*)(xbp + (size_t)cl*NSP + nl) = bv;
    // LDS transposed store with XOR swizzle: elem (c,n) at word n*64 + (c ^ (((n>>2)&7)<<2))
    float vv[4] = {v.x, v.y, v.z, v.w};
    #pragma unroll
    for (int j = 0; j < 4; ++j) {
      int n = nl + j;
      tile[n*64 + (cl ^ (((n>>2)&7)<<2))] = vv[j];
    }
  }
  __syncthreads();
  u16* xtp = xt + ((size_t)b*NSP + n0)*CH + c0;
  #pragma unroll
  for (int q = 0; q < 4; ++q) {
    int nl = grp + q*16;
    int c4 = lane16*4;
    float4 v = *(const float4*)&tile[nl*64 + (c4 ^ (((nl>>2)&7)<<2))];
    ushort4 bv; bv.x=f2b(v.x); bv.y=f2b(v.y); bv.z=f2b(v.z); bv.w=f2b(v.w);
    *(ushort4*)(xtp + (size_t)nl*CH + c4) = bv;
  }
}

// ---------------- kernel 2: per-batch Gram S = X X^T (bf16 MFMA, fp32 out)
// grid (2,2,BATCH) quadrants of 128x128, block 512 (8 waves, wave tile 32x64)
__global__ __launch_bounds__(512) void k_gram(const u16* __restrict__ xb, float* __restrict__ S) {
  const int b = blockIdx.z, qi = blockIdx.y, qj = blockIdx.x;
  const int t = threadIdx.x, w = t >> 6, l = t & 63;
  const int wm = w >> 1, wn = w & 1;
  const int m0 = qi*128 + wm*32, n0 = qj*128 + wn*64;
  const int lr = l & 15, lk = (l >> 4) * 8;
  const u16* xa = xb + (size_t)b*CH*NSP;
  f32x4 acc[2][4];
  #pragma unroll
  for (int i = 0; i < 2; ++i)
    #pragma unroll
    for (int j = 0; j < 4; ++j) acc[i][j] = (f32x4){0.f,0.f,0.f,0.f};
  for (int k = 0; k < NSP; k += 32) {
    bf16x8 A[2], Bf[4];
    #pragma unroll
    for (int mt = 0; mt < 2; ++mt)
      A[mt] = *(const bf16x8*)(xa + (size_t)(m0 + mt*16 + lr)*NSP + k + lk);
    #pragma unroll
    for (int nt = 0; nt < 4; ++nt)
      Bf[nt] = *(const bf16x8*)(xa + (size_t)(n0 + nt*16 + lr)*NSP + k + lk);
    #pragma unroll
    for (int mt = 0; mt < 2; ++mt)
      #pragma unroll
      for (int nt = 0; nt < 4; ++nt)
        acc[mt][nt] = __builtin_amdgcn_mfma_f32_16x16x32_bf16(A[mt], Bf[nt], acc[mt][nt], 0, 0, 0);
  }
  float* Sb = S + (size_t)b*CH*CH;
  const int r0 = (l >> 4) * 4;
  #pragma unroll
  for (int mt = 0; mt < 2; ++mt)
    #pragma unroll
    for (int nt = 0; nt < 4; ++nt)
      #pragma unroll
      for (int r = 0; r < 4; ++r)
        Sb[(size_t)(m0 + mt*16 + r0 + r)*CH + n0 + nt*16 + lr] = acc[mt][nt][r];
}

// ---------------- u = G s, v = Phi s  (per batch)
__global__ __launch_bounds__(256) void k_vecs(const float* __restrict__ svec,
    const float* __restrict__ g_w, const float* __restrict__ phi_w,
    float* __restrict__ uvec, float* __restrict__ vvec) {
  __shared__ float ls[CH];
  const int b = blockIdx.x, t = threadIdx.x;
  ls[t] = svec[b*CH + t];
  __syncthreads();
  const float* wrow = (t < CI) ? (g_w + (size_t)t*CH) : (phi_w + (size_t)(t - CI)*CH);
  float acc = 0.f;
  for (int c = 0; c < CH; ++c) acc += wrow[c] * ls[c];
  if (t < CI) uvec[b*CI + t] = acc; else vvec[b*CI + (t - CI)] = acc;
}

// ---------------- stage1: T1 = Phi @ S   [CI x CH]
__global__ __launch_bounds__(256) void k_s1(const float* __restrict__ S,
    const float* __restrict__ phi_w, float* __restrict__ T1) {
  __shared__ float lphi[8*CH];
  const int b = blockIdx.y, i0 = blockIdx.x*8, t = threadIdx.x;
  for (int idx = t; idx < 8*CH; idx += 256)
    lphi[idx] = phi_w[(size_t)(i0 + (idx >> 8))*CH + (idx & 255)];
  __syncthreads();
  const float* Sb = S + (size_t)b*CH*CH;
  float acc[8] = {0.f};
  for (int cp = 0; cp < CH; ++cp) {
    float sv = Sb[(size_t)cp*CH + t];
    #pragma unroll
    for (int r = 0; r < 8; ++r) acc[r] += lphi[r*CH + cp] * sv;
  }
  float* T1b = T1 + (size_t)b*CI*CH;
  #pragma unroll
  for (int r = 0; r < 8; ++r) T1b[(size_t)(i0 + r)*CH + t] = acc[r];
}

// ---------------- stage2: MT[j][i] = M^T, M = T1 G^T + v g_b^T + phi_b u^T + N phi_b g_b^T
__global__ __launch_bounds__(128) void k_s2(const float* __restrict__ T1,
    const float* __restrict__ g_w, const float* __restrict__ g_b,
    const float* __restrict__ phi_b, const float* __restrict__ uvec,
    const float* __restrict__ vvec, float* __restrict__ MT) {
  __shared__ float lt1[8*CH];
  const int b = blockIdx.y, i0 = blockIdx.x*8, j = threadIdx.x;
  const float* T1b = T1 + (size_t)b*CI*CH;
  for (int idx = j; idx < 8*CH; idx += 128)
    lt1[idx] = T1b[(size_t)(i0 + (idx >> 8))*CH + (idx & 255)];
  __syncthreads();
  float acc[8] = {0.f};
  for (int c = 0; c < CH; ++c) {
    float gv = g_w[(size_t)j*CH + c];
    #pragma unroll
    for (int r = 0; r < 8; ++r) acc[r] += lt1[r*CH + c] * gv;
  }
  const float gbj = g_b[j], uj = uvec[b*CI + j];
  float* MTb = MT + (size_t)b*CI*CI;
  #pragma unroll
  for (int r = 0; r < 8; ++r) {
    int i = i0 + r;
    MTb[(size_t)j*CI + i] = acc[r] + vvec[b*CI + i]*gbj + phi_b[i]*(uj + (float)NSP*gbj);
  }
}

// ---------------- stage3: T2[co][i] = sum_j w_w[co][j] * MT[j][i]
__global__ __launch_bounds__(128) void k_s3(const float* __restrict__ MT,
    const float* __restrict__ w_w, float* __restrict__ T2) {
  __shared__ float lw[8*CI];
  const int b = blockIdx.y, co0 = blockIdx.x*8, i = threadIdx.x;
  for (int idx = i; idx < 8*CI; idx += 128)
    lw[idx] = w_w[(size_t)(co0 + (idx >> 7))*CI + (idx & 127)];
  __syncthreads();
  const float* MTb = MT + (size_t)b*CI*CI;
  float acc[8] = {0.f};
  for (int j = 0; j < CI; ++j) {
    float mv = MTb[(size_t)j*CI + i];
    #pragma unroll
    for (int r = 0; r < 8; ++r) acc[r] += lw[r*CI + j] * mv;
  }
  float* T2b = T2 + (size_t)b*CH*CI;
  #pragma unroll
  for (int r = 0; r < 8; ++r) T2b[(size_t)(co0 + r)*CI + i] = acc[r];
}

// ---------------- stage4: P[co][c] = inv[co]/N * sum_i T2[co][i] theta_w[i][c]  -> bf16
__global__ __launch_bounds__(256) void k_s4(const float* __restrict__ T2,
    const float* __restrict__ theta_w, const float* __restrict__ bn_gamma,
    const float* __restrict__ bn_var, u16* __restrict__ Pb) {
  __shared__ float lt2[8*CI];
  const int b = blockIdx.y, co0 = blockIdx.x*8, c = threadIdx.x;
  const float* T2b = T2 + (size_t)b*CH*CI;
  for (int idx = c; idx < 8*CI; idx += 256)
    lt2[idx] = T2b[(size_t)(co0 + (idx >> 7))*CI + (idx & 127)];
  __syncthreads();
  float acc[8] = {0.f};
  for (int i = 0; i < CI; ++i) {
    float th = theta_w[(size_t)i*CH + c];
    #pragma unroll
    for (int r = 0; r < 8; ++r) acc[r] += lt2[r*CI + i] * th;
  }
  u16* Pbb = Pb + (size_t)b*CH*CH;
  #pragma unroll
  for (int r = 0; r < 8; ++r) {
    int co = co0 + r;
    float inv = bn_gamma[co] * rsqrtf(bn_var[co] + EPSV);
    Pbb[(size_t)co*CH + c] = f2b(acc[r] * inv * (1.f/(float)NSP));
  }
}

// ---------------- stage4b: per-channel constant d
__global__ __launch_bounds__(256) void k_s4b(const float* __restrict__ T2,
    const float* __restrict__ theta_b, const float* __restrict__ w_b,
    const float* __restrict__ bn_gamma, const float* __restrict__ bn_beta,
    const float* __restrict__ bn_mean, const float* __restrict__ bn_var,
    float* __restrict__ dv) {
  const int b = blockIdx.x, co = threadIdx.x;
  const float* row = T2 + (size_t)b*CH*CI + (size_t)co*CI;
  float dot = 0.f;
  for (int i = 0; i < CI; ++i) dot += row[i] * theta_b[i];
  float inv = bn_gamma[co] * rsqrtf(bn_var[co] + EPSV);
  dv[b*CH + co] = inv*(dot*(1.f/(float)NSP) + w_b[co]) + bn_beta[co] - bn_mean[co]*inv;
}

// ---------------- apply: out = X + P X + d 1^T   (bf16 MFMA, fp32 residual)
// grid (NSP/64, BATCH), block 256 (4 waves, wave tile 64rows x 64cols)
__global__ __launch_bounds__(256) void k_apply(const u16* __restrict__ Pb,
    const u16* __restrict__ xt, const float* __restrict__ x,
    const float* __restrict__ dv, float* __restrict__ out) {
  const int b = blockIdx.y, n0 = blockIdx.x*64;
  const int t = threadIdx.x, w = t >> 6, l = t & 63;
  const int m0 = w*64;
  const int lr = l & 15, lk = (l >> 4) * 8;
  const u16* Pp = Pb + (size_t)b*CH*CH;
  const u16* Xt = xt + (size_t)b*NSP*CH;
  f32x4 acc[4][4];
  #pragma unroll
  for (int i = 0; i < 4; ++i)
    #pragma unroll
    for (int j = 0; j < 4; ++j) acc[i][j] = (f32x4){0.f,0.f,0.f,0.f};
  #pragma unroll
  for (int k = 0; k < CH; k += 32) {
    bf16x8 A[4], Bf[4];
    #pragma unroll
    for (int mt = 0; mt < 4; ++mt)
      A[mt] = *(const bf16x8*)(Pp + (size_t)(m0 + mt*16 + lr)*CH + k + lk);
    #pragma unroll
    for (int nt = 0; nt < 4; ++nt)
      Bf[nt] = *(const bf16x8*)(Xt + (size_t)(n0 + nt*16 + lr)*CH + k + lk);
    #pragma unroll
    for (int mt = 0; mt < 4; ++mt)
      #pragma unroll
      for (int nt = 0; nt < 4; ++nt)
        acc[mt][nt] = __builtin_amdgcn_mfma_f32_16x16x32_bf16(A[mt], Bf[nt], acc[mt][nt], 0, 0, 0);
  }
  const float* xpb = x + (size_t)b*CH*NSP;
  float* ob = out + (size_t)b*CH*NSP;
  const int r0 = (l >> 4) * 4;
  #pragma unroll
  for (int mt = 0; mt < 4; ++mt)
    #pragma unroll
    for (int r = 0; r < 4; ++r) {
      int row = m0 + mt*16 + r0 + r;
      float dval = dv[b*CH + row];
      #pragma unroll
      for (int nt = 0; nt < 4; ++nt) {
        int col = n0 + nt*16 + lr;
        ob[(size_t)row*NSP + col] = acc[mt][nt][r] + xpb[(size_t)row*NSP + col] + dval;
      }
    }
}

// ---------------- workspace layout (bytes)
static constexpr size_t XT_OFF = 0;                       // bf16 [16][4096][256]  33,554,432
static constexpr size_t S_OFF  = 33554432;                // f32  [16][256][256]    4,194,304
static constexpr size_t T1_OFF = 37748736;                // f32  [16][128][256]    2,097,152
static constexpr size_t MT_OFF = 39845888;                // f32  [16][128][128]    1,048,576
static constexpr size_t T2_OFF = 40894464;                // f32  [16][256][128]    2,097,152
static constexpr size_t PB_OFF = 42991616;                // bf16 [16][256][256]    2,097,152
static constexpr size_t SV_OFF = 45088768;                // f32  [16][256]            16,384
static constexpr size_t UV_OFF = 45105152;                // f32  [16][128]             8,192
static constexpr size_t VV_OFF = 45113344;                // f32  [16][128]             8,192
static constexpr size_t DV_OFF = 45121536;                // f32  [16][256]            16,384

extern "C" void kernel_launch(void* const* d_in, const int* in_sizes, int n_in,
                              void* d_out, int out_size, void* d_ws, size_t ws_size,
                              hipStream_t stream) {
  const float* x       = (const float*)d_in[0];
  const float* g_w     = (const float*)d_in[1];
  const float* g_b     = (const float*)d_in[2];
  const float* theta_w = (const float*)d_in[3];
  const float* theta_b = (const float*)d_in[4];
  const float* phi_w   = (const float*)d_in[5];
  const float* phi_b   = (const float*)d_in[6];
  const float* w_w     = (const float*)d_in[7];
  const float* w_b     = (const float*)d_in[8];
  const float* bn_g    = (const float*)d_in[9];
  const float* bn_b    = (const float*)d_in[10];
  const float* bn_m    = (const float*)d_in[11];
  const float* bn_v    = (const float*)d_in[12];
  float* out = (float*)d_out;
  char* ws = (char*)d_ws;
  u16*   XT = (u16*)(ws + XT_OFF);
  float* S  = (float*)(ws + S_OFF);
  float* T1 = (float*)(ws + T1_OFF);
  float* MT = (float*)(ws + MT_OFF);
  float* T2 = (float*)(ws + T2_OFF);
  u16*   Pb = (u16*)(ws + PB_OFF);
  float* SV = (float*)(ws + SV_OFF);
  float* UV = (float*)(ws + UV_OFF);
  float* VV = (float*)(ws + VV_OFF);
  float* DV = (float*)(ws + DV_OFF);
  // bf16 row-major X staging lives in d_out; it is fully dead before k_apply rewrites out.
  u16* Xb = (u16*)d_out;

  hipMemsetAsync(SV, 0, BATCH*CH*sizeof(float), stream);
  k_prep <<<dim3(NSP/64, CH/64, BATCH), 256, 0, stream>>>(x, Xb, XT, SV);
  k_gram <<<dim3(2, 2, BATCH),          512, 0, stream>>>(Xb, S);
  k_vecs <<<dim3(BATCH),                256, 0, stream>>>(SV, g_w, phi_w, UV, VV);
  k_s1   <<<dim3(16, BATCH),            256, 0, stream>>>(S, phi_w, T1);
  k_s2   <<<dim3(16, BATCH),            128, 0, stream>>>(T1, g_w, g_b, phi_b, UV, VV, MT);
  k_s3   <<<dim3(32, BATCH),            128, 0, stream>>>(MT, w_w, T2);
  k_s4   <<<dim3(32, BATCH),            256, 0, stream>>>(T2, theta_w, bn_g, bn_v, Pb);
  k_s4b  <<<dim3(BATCH),                256, 0, stream>>>(T2, theta_b, w_b, bn_g, bn_b, bn_m, bn_v, DV);
  k_apply<<<dim3(NSP/64, BATCH),        256, 0, stream>>>(Pb, XT, x, DV, out);
}

// Round 2
// 226.424 us; speedup vs baseline: 1.5070x; 1.5070x over previous
//
#include <hip/hip_runtime.h>
#include <stdint.h>

#define BATCH 16
#define CH    256
#define CI    128
#define NSP   4096
#define KC    8          // K-split chunks for the Gram GEMM
#define EPSV  1e-5f

typedef unsigned short u16;
typedef __attribute__((ext_vector_type(4))) float f32x4;
typedef __attribute__((ext_vector_type(8))) short bf16x8;

__device__ __forceinline__ u16 f2b(float f) {
  uint32_t u = __float_as_uint(f);
  uint32_t r = u + 0x7FFFu + ((u >> 16) & 1u);   // round-to-nearest-even
  return (u16)(r >> 16);
}

// ---------------- kernel 1: bf16 convert (row-major + transposed) + row sums
// grid (NSP/64, CH/64, BATCH), block 256
__global__ __launch_bounds__(256) void k_prep(const float* __restrict__ x,
    u16* __restrict__ xb, u16* __restrict__ xt, float* __restrict__ svec) {
  __shared__ float tile[64*64];
  const int b = blockIdx.z, c0 = blockIdx.y*64, n0 = blockIdx.x*64;
  const int t = threadIdx.x;
  const int lane16 = t & 15;
  const int grp = t >> 4;              // 0..15
  const float* xp = x + ((size_t)b*CH + c0)*NSP + n0;
  u16* xbp = xb + ((size_t)b*CH + c0)*NSP + n0;
  #pragma unroll
  for (int p = 0; p < 4; ++p) {
    int cl = grp + p*16;               // row within tile, 0..63
    int nl = lane16*4;
    float4 v = *(const float4*)(xp + (size_t)cl*NSP + nl);
    // row-sum partial (16 lanes per row are consecutive)
    float ps = v.x + v.y + v.z + v.w;
    #pragma unroll
    for (int o = 1; o < 16; o <<= 1) ps += __shfl_xor(ps, o, 64);
    if (lane16 == 0) atomicAdd(&svec[b*CH + c0 + cl], ps);
    // bf16 row-major store
    ushort4 bv; bv.x=f2b(v.x); bv.y=f2b(v.y); bv.z=f2b(v.z); bv.w=f2b(v.w);
    *(ushort4*)(xbp + (size_t)cl*NSP + nl) = bv;
    // LDS transposed store with XOR swizzle: elem (c,n) at word n*64 + (c ^ (((n>>2)&7)<<2))
    float vv[4] = {v.x, v.y, v.z, v.w};
    #pragma unroll
    for (int j = 0; j < 4; ++j) {
      int n = nl + j;
      tile[n*64 + (cl ^ (((n>>2)&7)<<2))] = vv[j];
    }
  }
  __syncthreads();
  u16* xtp = xt + ((size_t)b*NSP + n0)*CH + c0;
  #pragma unroll
  for (int q = 0; q < 4; ++q) {
    int nl = grp + q*16;
    int c4 = lane16*4;
    float4 v = *(const float4*)&tile[nl*64 + (c4 ^ (((nl>>2)&7)<<2))];
    ushort4 bv; bv.x=f2b(v.x); bv.y=f2b(v.y); bv.z=f2b(v.z); bv.w=f2b(v.w);
    *(ushort4*)(xtp + (size_t)nl*CH + c4) = bv;
  }
}

// ---------------- kernel 2: per-batch Gram partials Sp[b][kc] = X[:,kc] X[:,kc]^T
// grid (2,2,BATCH*KC) quadrants of 128x128, block 512 (8 waves, wave tile 32x64)
__global__ __launch_bounds__(512) void k_gram(const u16* __restrict__ xb, float* __restrict__ Sp) {
  const int bz = blockIdx.z, b = bz >> 3, kc = bz & (KC-1);
  const int qi = blockIdx.y, qj = blockIdx.x;
  const int t = threadIdx.x, w = t >> 6, l = t & 63;
  const int wm = w >> 1, wn = w & 1;
  const int m0 = qi*128 + wm*32, n0 = qj*128 + wn*64;
  const int lr = l & 15, lk = (l >> 4) * 8;
  const u16* xa = xb + (size_t)b*CH*NSP;
  f32x4 acc[2][4];
  #pragma unroll
  for (int i = 0; i < 2; ++i)
    #pragma unroll
    for (int j = 0; j < 4; ++j) acc[i][j] = (f32x4){0.f,0.f,0.f,0.f};
  const int kbeg = kc * (NSP/KC), kend = kbeg + (NSP/KC);
  for (int k = kbeg; k < kend; k += 32) {
    bf16x8 A[2], Bf[4];
    #pragma unroll
    for (int mt = 0; mt < 2; ++mt)
      A[mt] = *(const bf16x8*)(xa + (size_t)(m0 + mt*16 + lr)*NSP + k + lk);
    #pragma unroll
    for (int nt = 0; nt < 4; ++nt)
      Bf[nt] = *(const bf16x8*)(xa + (size_t)(n0 + nt*16 + lr)*NSP + k + lk);
    #pragma unroll
    for (int mt = 0; mt < 2; ++mt)
      #pragma unroll
      for (int nt = 0; nt < 4; ++nt)
        acc[mt][nt] = __builtin_amdgcn_mfma_f32_16x16x32_bf16(A[mt], Bf[nt], acc[mt][nt], 0, 0, 0);
  }
  float* Sb = Sp + (size_t)bz*CH*CH;
  const int r0 = (l >> 4) * 4;
  #pragma unroll
  for (int mt = 0; mt < 2; ++mt)
    #pragma unroll
    for (int nt = 0; nt < 4; ++nt)
      #pragma unroll
      for (int r = 0; r < 4; ++r)
        Sb[(size_t)(m0 + mt*16 + r0 + r)*CH + n0 + nt*16 + lr] = acc[mt][nt][r];
}

// ---------------- reduce partials: S[b] = sum_kc Sp[b][kc]  (deterministic order)
// grid (CH*CH/256, BATCH), block 256
__global__ __launch_bounds__(256) void k_red(const float* __restrict__ Sp, float* __restrict__ S) {
  const int b = blockIdx.y;
  const size_t i = (size_t)blockIdx.x*256 + threadIdx.x;
  const float* p = Sp + (size_t)b*KC*CH*CH + i;
  float s = 0.f;
  #pragma unroll
  for (int kc = 0; kc < KC; ++kc) s += p[(size_t)kc*CH*CH];
  S[(size_t)b*CH*CH + i] = s;
}

// ---------------- u = G s, v = Phi s  (per batch)
__global__ __launch_bounds__(256) void k_vecs(const float* __restrict__ svec,
    const float* __restrict__ g_w, const float* __restrict__ phi_w,
    float* __restrict__ uvec, float* __restrict__ vvec) {
  __shared__ float ls[CH];
  const int b = blockIdx.x, t = threadIdx.x;
  ls[t] = svec[b*CH + t];
  __syncthreads();
  const float* wrow = (t < CI) ? (g_w + (size_t)t*CH) : (phi_w + (size_t)(t - CI)*CH);
  float acc = 0.f;
  for (int c = 0; c < CH; ++c) acc += wrow[c] * ls[c];
  if (t < CI) uvec[b*CI + t] = acc; else vvec[b*CI + (t - CI)] = acc;
}

// ---------------- stage1: T1 = Phi @ S   [CI x CH]
__global__ __launch_bounds__(256) void k_s1(const float* __restrict__ S,
    const float* __restrict__ phi_w, float* __restrict__ T1) {
  __shared__ float lphi[8*CH];
  const int b = blockIdx.y, i0 = blockIdx.x*8, t = threadIdx.x;
  for (int idx = t; idx < 8*CH; idx += 256)
    lphi[idx] = phi_w[(size_t)(i0 + (idx >> 8))*CH + (idx & 255)];
  __syncthreads();
  const float* Sb = S + (size_t)b*CH*CH;
  float acc[8] = {0.f};
  for (int cp = 0; cp < CH; ++cp) {
    float sv = Sb[(size_t)cp*CH + t];
    #pragma unroll
    for (int r = 0; r < 8; ++r) acc[r] += lphi[r*CH + cp] * sv;
  }
  float* T1b = T1 + (size_t)b*CI*CH;
  #pragma unroll
  for (int r = 0; r < 8; ++r) T1b[(size_t)(i0 + r)*CH + t] = acc[r];
}

// ---------------- stage2: MT[j][i] = M^T, M = T1 G^T + v g_b^T + phi_b u^T + N phi_b g_b^T
__global__ __launch_bounds__(128) void k_s2(const float* __restrict__ T1,
    const float* __restrict__ g_w, const float* __restrict__ g_b,
    const float* __restrict__ phi_b, const float* __restrict__ uvec,
    const float* __restrict__ vvec, float* __restrict__ MT) {
  __shared__ float lt1[8*CH];
  const int b = blockIdx.y, i0 = blockIdx.x*8, j = threadIdx.x;
  const float* T1b = T1 + (size_t)b*CI*CH;
  for (int idx = j; idx < 8*CH; idx += 128)
    lt1[idx] = T1b[(size_t)(i0 + (idx >> 8))*CH + (idx & 255)];
  __syncthreads();
  float acc[8] = {0.f};
  for (int c = 0; c < CH; ++c) {
    float gv = g_w[(size_t)j*CH + c];
    #pragma unroll
    for (int r = 0; r < 8; ++r) acc[r] += lt1[r*CH + c] * gv;
  }
  const float gbj = g_b[j], uj = uvec[b*CI + j];
  float* MTb = MT + (size_t)b*CI*CI;
  #pragma unroll
  for (int r = 0; r < 8; ++r) {
    int i = i0 + r;
    MTb[(size_t)j*CI + i] = acc[r] + vvec[b*CI + i]*gbj + phi_b[i]*(uj + (float)NSP*gbj);
  }
}

// ---------------- stage3: T2[co][i] = sum_j w_w[co][j] * MT[j][i]
__global__ __launch_bounds__(128) void k_s3(const float* __restrict__ MT,
    const float* __restrict__ w_w, float* __restrict__ T2) {
  __shared__ float lw[8*CI];
  const int b = blockIdx.y, co0 = blockIdx.x*8, i = threadIdx.x;
  for (int idx = i; idx < 8*CI; idx += 128)
    lw[idx] = w_w[(size_t)(co0 + (idx >> 7))*CI + (idx & 127)];
  __syncthreads();
  const float* MTb = MT + (size_t)b*CI*CI;
  float acc[8] = {0.f};
  for (int j = 0; j < CI; ++j) {
    float mv = MTb[(size_t)j*CI + i];
    #pragma unroll
    for (int r = 0; r < 8; ++r) acc[r] += lw[r*CI + j] * mv;
  }
  float* T2b = T2 + (size_t)b*CH*CI;
  #pragma unroll
  for (int r = 0; r < 8; ++r) T2b[(size_t)(co0 + r)*CI + i] = acc[r];
}

// ---------------- stage4: P[co][c] = inv[co]/N * sum_i T2[co][i] theta_w[i][c]  -> bf16
__global__ __launch_bounds__(256) void k_s4(const float* __restrict__ T2,
    const float* __restrict__ theta_w, const float* __restrict__ bn_gamma,
    const float* __restrict__ bn_var, u16* __restrict__ Pb) {
  __shared__ float lt2[8*CI];
  const int b = blockIdx.y, co0 = blockIdx.x*8, c = threadIdx.x;
  const float* T2b = T2 + (size_t)b*CH*CI;
  for (int idx = c; idx < 8*CI; idx += 256)
    lt2[idx] = T2b[(size_t)(co0 + (idx >> 7))*CI + (idx & 127)];
  __syncthreads();
  float acc[8] = {0.f};
  for (int i = 0; i < CI; ++i) {
    float th = theta_w[(size_t)i*CH + c];
    #pragma unroll
    for (int r = 0; r < 8; ++r) acc[r] += lt2[r*CI + i] * th;
  }
  u16* Pbb = Pb + (size_t)b*CH*CH;
  #pragma unroll
  for (int r = 0; r < 8; ++r) {
    int co = co0 + r;
    float inv = bn_gamma[co] * rsqrtf(bn_var[co] + EPSV);
    Pbb[(size_t)co*CH + c] = f2b(acc[r] * inv * (1.f/(float)NSP));
  }
}

// ---------------- stage4b: per-channel constant d
__global__ __launch_bounds__(256) void k_s4b(const float* __restrict__ T2,
    const float* __restrict__ theta_b, const float* __restrict__ w_b,
    const float* __restrict__ bn_gamma, const float* __restrict__ bn_beta,
    const float* __restrict__ bn_mean, const float* __restrict__ bn_var,
    float* __restrict__ dv) {
  const int b = blockIdx.x, co = threadIdx.x;
  const float* row = T2 + (size_t)b*CH*CI + (size_t)co*CI;
  float dot = 0.f;
  for (int i = 0; i < CI; ++i) dot += row[i] * theta_b[i];
  float inv = bn_gamma[co] * rsqrtf(bn_var[co] + EPSV);
  dv[b*CH + co] = inv*(dot*(1.f/(float)NSP) + w_b[co]) + bn_beta[co] - bn_mean[co]*inv;
}

// ---------------- apply: out = X + P X + d 1^T   (bf16 MFMA, fp32 residual)
// grid (NSP/64, BATCH), block 256 (4 waves, wave tile 64rows x 64cols)
__global__ __launch_bounds__(256) void k_apply(const u16* __restrict__ Pb,
    const u16* __restrict__ xt, const float* __restrict__ x,
    const float* __restrict__ dv, float* __restrict__ out) {
  const int b = blockIdx.y, n0 = blockIdx.x*64;
  const int t = threadIdx.x, w = t >> 6, l = t & 63;
  const int m0 = w*64;
  const int lr = l & 15, lk = (l >> 4) * 8;
  const u16* Pp = Pb + (size_t)b*CH*CH;
  const u16* Xt = xt + (size_t)b*NSP*CH;
  f32x4 acc[4][4];
  #pragma unroll
  for (int i = 0; i < 4; ++i)
    #pragma unroll
    for (int j = 0; j < 4; ++j) acc[i][j] = (f32x4){0.f,0.f,0.f,0.f};
  #pragma unroll
  for (int k = 0; k < CH; k += 32) {
    bf16x8 A[4], Bf[4];
    #pragma unroll
    for (int mt = 0; mt < 4; ++mt)
      A[mt] = *(const bf16x8*)(Pp + (size_t)(m0 + mt*16 + lr)*CH + k + lk);
    #pragma unroll
    for (int nt = 0; nt < 4; ++nt)
      Bf[nt] = *(const bf16x8*)(Xt + (size_t)(n0 + nt*16 + lr)*CH + k + lk);
    #pragma unroll
    for (int mt = 0; mt < 4; ++mt)
      #pragma unroll
      for (int nt = 0; nt < 4; ++nt)
        acc[mt][nt] = __builtin_amdgcn_mfma_f32_16x16x32_bf16(A[mt], Bf[nt], acc[mt][nt], 0, 0, 0);
  }
  const float* xpb = x + (size_t)b*CH*NSP;
  float* ob = out + (size_t)b*CH*NSP;
  const int r0 = (l >> 4) * 4;
  #pragma unroll
  for (int mt = 0; mt < 4; ++mt)
    #pragma unroll
    for (int r = 0; r < 4; ++r) {
      int row = m0 + mt*16 + r0 + r;
      float dval = dv[b*CH + row];
      #pragma unroll
      for (int nt = 0; nt < 4; ++nt) {
        int col = n0 + nt*16 + lr;
        ob[(size_t)row*NSP + col] = acc[mt][nt][r] + xpb[(size_t)row*NSP + col] + dval;
      }
    }
}

// ---------------- workspace layout (bytes)
static constexpr size_t XT_OFF = 0;                       // bf16 [16][4096][256]  33,554,432
static constexpr size_t S_OFF  = 33554432;                // f32  [16][256][256]    4,194,304
static constexpr size_t T1_OFF = 37748736;                // f32  [16][128][256]    2,097,152
static constexpr size_t MT_OFF = 39845888;                // f32  [16][128][128]    1,048,576
static constexpr size_t T2_OFF = 40894464;                // f32  [16][256][128]    2,097,152
static constexpr size_t PB_OFF = 42991616;                // bf16 [16][256][256]    2,097,152
static constexpr size_t SV_OFF = 45088768;                // f32  [16][256]            16,384
static constexpr size_t UV_OFF = 45105152;                // f32  [16][128]             8,192
static constexpr size_t VV_OFF = 45113344;                // f32  [16][128]             8,192
static constexpr size_t DV_OFF = 45121536;                // f32  [16][256]            16,384

extern "C" void kernel_launch(void* const* d_in, const int* in_sizes, int n_in,
                              void* d_out, int out_size, void* d_ws, size_t ws_size,
                              hipStream_t stream) {
  const float* x       = (const float*)d_in[0];
  const float* g_w     = (const float*)d_in[1];
  const float* g_b     = (const float*)d_in[2];
  const float* theta_w = (const float*)d_in[3];
  const float* theta_b = (const float*)d_in[4];
  const float* phi_w   = (const float*)d_in[5];
  const float* phi_b   = (const float*)d_in[6];
  const float* w_w     = (const float*)d_in[7];
  const float* w_b     = (const float*)d_in[8];
  const float* bn_g    = (const float*)d_in[9];
  const float* bn_b    = (const float*)d_in[10];
  const float* bn_m    = (const float*)d_in[11];
  const float* bn_v    = (const float*)d_in[12];
  float* out = (float*)d_out;
  char* ws = (char*)d_ws;
  u16*   XT = (u16*)(ws + XT_OFF);
  float* S  = (float*)(ws + S_OFF);
  float* T1 = (float*)(ws + T1_OFF);
  float* MT = (float*)(ws + MT_OFF);
  float* T2 = (float*)(ws + T2_OFF);
  u16*   Pb = (u16*)(ws + PB_OFF);
  float* SV = (float*)(ws + SV_OFF);
  float* UV = (float*)(ws + UV_OFF);
  float* VV = (float*)(ws + VV_OFF);
  float* DV = (float*)(ws + DV_OFF);
  // bf16 row-major X staging lives in the LOWER half of d_out (33.5 MB);
  // Gram K-split partials (16*8*256*256 f32 = 33.5 MB) live in the UPPER half.
  // Both are dead before k_apply rewrites d_out.
  u16*   Xb = (u16*)d_out;
  float* Sp = (float*)((char*)d_out + 33554432);

  hipMemsetAsync(SV, 0, BATCH*CH*sizeof(float), stream);
  k_prep <<<dim3(NSP/64, CH/64, BATCH),  256, 0, stream>>>(x, Xb, XT, SV);
  k_gram <<<dim3(2, 2, BATCH*KC),        512, 0, stream>>>(Xb, Sp);
  k_red  <<<dim3(CH*CH/256, BATCH),      256, 0, stream>>>(Sp, S);
  k_vecs <<<dim3(BATCH),                 256, 0, stream>>>(SV, g_w, phi_w, UV, VV);
  k_s1   <<<dim3(16, BATCH),             256, 0, stream>>>(S, phi_w, T1);
  k_s2   <<<dim3(16, BATCH),             128, 0, stream>>>(T1, g_w, g_b, phi_b, UV, VV, MT);
  k_s3   <<<dim3(32, BATCH),             128, 0, stream>>>(MT, w_w, T2);
  k_s4   <<<dim3(32, BATCH),             256, 0, stream>>>(T2, theta_w, bn_g, bn_v, Pb);
  k_s4b  <<<dim3(BATCH),                 256, 0, stream>>>(T2, theta_b, w_b, bn_g, bn_b, bn_m, bn_v, DV);
  k_apply<<<dim3(NSP/64, BATCH),         256, 0, stream>>>(Pb, XT, x, DV, out);
}

// Round 3
// 177.141 us; speedup vs baseline: 1.9263x; 1.2782x over previous
//
#include <hip/hip_runtime.h>
#include <stdint.h>

#define BATCH 16
#define CH    256
#define CI    128
#define NSP   4096
#define KC    8          // K-split chunks for the Gram GEMM
#define EPSV  1e-5f

typedef unsigned short u16;
typedef __attribute__((ext_vector_type(4))) float f32x4;
typedef __attribute__((ext_vector_type(8))) short bf16x8;

__device__ __forceinline__ u16 f2b(float f) {
  uint32_t u = __float_as_uint(f);
  uint32_t r = u + 0x7FFFu + ((u >> 16) & 1u);   // round-to-nearest-even
  return (u16)(r >> 16);
}

// ---------------- k_const: batch-independent matrices/vectors
// E = w_w @ g_w [256x256], KT[a][c] = sum_i phi_w[i][a]*theta_w[i][c]
// wg = w_w@g_b, tphi = theta^T phi_b, q = phi^T theta_b, inv, dconst, tb = theta_b.phi_b
__global__ __launch_bounds__(256) void k_const(const float* __restrict__ w_w,
    const float* __restrict__ g_w, const float* __restrict__ g_b,
    const float* __restrict__ theta_w, const float* __restrict__ theta_b,
    const float* __restrict__ phi_w, const float* __restrict__ phi_b,
    const float* __restrict__ w_b, const float* __restrict__ bn_g,
    const float* __restrict__ bn_b, const float* __restrict__ bn_m,
    const float* __restrict__ bn_v,
    float* __restrict__ E, float* __restrict__ KT, float* __restrict__ wg,
    float* __restrict__ tphi, float* __restrict__ q, float* __restrict__ inv,
    float* __restrict__ dconst, float* __restrict__ tb) {
  __shared__ float lbuf[1024];
  const int blk = blockIdx.x, t = threadIdx.x;
  if (blk < 32) {                 // E rows o0..o0+7
    const int o0 = blk*8;
    #pragma unroll
    for (int k = 0; k < 4; ++k) { int idx = k*256 + t;
      lbuf[idx] = w_w[(size_t)(o0 + (idx & 7))*CI + (idx >> 3)]; }
    __syncthreads();
    float acc[8] = {0.f};
    for (int j = 0; j < CI; ++j) {
      float gv = g_w[(size_t)j*CH + t];
      #pragma unroll
      for (int r = 0; r < 8; ++r) acc[r] += lbuf[j*8 + r] * gv;
    }
    #pragma unroll
    for (int r = 0; r < 8; ++r) E[(size_t)(o0 + r)*CH + t] = acc[r];
  } else if (blk < 64) {          // KT rows a0..a0+7
    const int a0 = (blk - 32)*8;
    #pragma unroll
    for (int k = 0; k < 4; ++k) { int idx = k*256 + t;
      lbuf[idx] = phi_w[(size_t)(idx >> 3)*CH + a0 + (idx & 7)]; }
    __syncthreads();
    float acc[8] = {0.f};
    for (int i = 0; i < CI; ++i) {
      float tv = theta_w[(size_t)i*CH + t];
      #pragma unroll
      for (int u = 0; u < 8; ++u) acc[u] += lbuf[i*8 + u] * tv;
    }
    #pragma unroll
    for (int u = 0; u < 8; ++u) KT[(size_t)(a0 + u)*CH + t] = acc[u];
  } else {                        // vectors
    float iv = bn_g[t] * rsqrtf(bn_v[t] + EPSV);
    inv[t] = iv;
    dconst[t] = iv*w_b[t] + bn_b[t] - bn_m[t]*iv;
    float a = 0.f;
    for (int j = 0; j < CI; ++j) a += w_w[(size_t)t*CI + j] * g_b[j];
    wg[t] = a;
    float tp = 0.f, qq = 0.f;
    for (int i = 0; i < CI; ++i) {
      tp += theta_w[(size_t)i*CH + t] * phi_b[i];
      qq += phi_w[(size_t)i*CH + t] * theta_b[i];
    }
    tphi[t] = tp; q[t] = qq;
    lbuf[t] = (t < CI) ? theta_b[t]*phi_b[t] : 0.f;
    __syncthreads();
    for (int s2 = 128; s2 > 0; s2 >>= 1) { if (t < s2) lbuf[t] += lbuf[t + s2]; __syncthreads(); }
    if (t == 0) tb[0] = lbuf[0];
  }
}

// ---------------- kernel 1: bf16 convert (row-major + transposed) + row-sum partials
// grid (NSP/64, CH/64, BATCH), block 256
__global__ __launch_bounds__(256) void k_prep(const float* __restrict__ x,
    u16* __restrict__ xb, u16* __restrict__ xt, float* __restrict__ psum) {
  __shared__ float tile[64*64];
  const int b = blockIdx.z, c0 = blockIdx.y*64, n0 = blockIdx.x*64;
  const int t = threadIdx.x;
  const int lane16 = t & 15;
  const int grp = t >> 4;              // 0..15
  const float* xp = x + ((size_t)b*CH + c0)*NSP + n0;
  u16* xbp = xb + ((size_t)b*CH + c0)*NSP + n0;
  #pragma unroll
  for (int p = 0; p < 4; ++p) {
    int cl = grp + p*16;               // row within tile, 0..63
    int nl = lane16*4;
    float4 v = *(const float4*)(xp + (size_t)cl*NSP + nl);
    float ps = v.x + v.y + v.z + v.w;
    #pragma unroll
    for (int o = 1; o < 16; o <<= 1) ps += __shfl_xor(ps, o, 64);
    if (lane16 == 0) psum[((size_t)b*64 + blockIdx.x)*CH + c0 + cl] = ps;
    ushort4 bv; bv.x=f2b(v.x); bv.y=f2b(v.y); bv.z=f2b(v.z); bv.w=f2b(v.w);
    *(ushort4*)(xbp + (size_t)cl*NSP + nl) = bv;
    float vv[4] = {v.x, v.y, v.z, v.w};
    #pragma unroll
    for (int j = 0; j < 4; ++j) {
      int n = nl + j;
      tile[n*64 + (cl ^ (((n>>2)&7)<<2))] = vv[j];
    }
  }
  __syncthreads();
  u16* xtp = xt + ((size_t)b*NSP + n0)*CH + c0;
  #pragma unroll
  for (int q2 = 0; q2 < 4; ++q2) {
    int nl = grp + q2*16;
    int c4 = lane16*4;
    float4 v = *(const float4*)&tile[nl*64 + (c4 ^ (((nl>>2)&7)<<2))];
    ushort4 bv; bv.x=f2b(v.x); bv.y=f2b(v.y); bv.z=f2b(v.z); bv.w=f2b(v.w);
    *(ushort4*)(xtp + (size_t)nl*CH + c4) = bv;
  }
}

// ---------------- kernel 2: per-batch Gram partials Sp[b][kc] = X[:,kc] X[:,kc]^T
__global__ __launch_bounds__(512) void k_gram(const u16* __restrict__ xb, float* __restrict__ Sp) {
  const int bz = blockIdx.z, b = bz >> 3, kc = bz & (KC-1);
  const int qi = blockIdx.y, qj = blockIdx.x;
  const int t = threadIdx.x, w = t >> 6, l = t & 63;
  const int wm = w >> 1, wn = w & 1;
  const int m0 = qi*128 + wm*32, n0 = qj*128 + wn*64;
  const int lr = l & 15, lk = (l >> 4) * 8;
  const u16* xa = xb + (size_t)b*CH*NSP;
  f32x4 acc[2][4];
  #pragma unroll
  for (int i = 0; i < 2; ++i)
    #pragma unroll
    for (int j = 0; j < 4; ++j) acc[i][j] = (f32x4){0.f,0.f,0.f,0.f};
  const int kbeg = kc * (NSP/KC), kend = kbeg + (NSP/KC);
  #pragma unroll 4
  for (int k = kbeg; k < kend; k += 32) {
    bf16x8 A[2], Bf[4];
    #pragma unroll
    for (int mt = 0; mt < 2; ++mt)
      A[mt] = *(const bf16x8*)(xa + (size_t)(m0 + mt*16 + lr)*NSP + k + lk);
    #pragma unroll
    for (int nt = 0; nt < 4; ++nt)
      Bf[nt] = *(const bf16x8*)(xa + (size_t)(n0 + nt*16 + lr)*NSP + k + lk);
    #pragma unroll
    for (int mt = 0; mt < 2; ++mt)
      #pragma unroll
      for (int nt = 0; nt < 4; ++nt)
        acc[mt][nt] = __builtin_amdgcn_mfma_f32_16x16x32_bf16(A[mt], Bf[nt], acc[mt][nt], 0, 0, 0);
  }
  float* Sb = Sp + (size_t)bz*CH*CH;
  const int r0 = (l >> 4) * 4;
  #pragma unroll
  for (int mt = 0; mt < 2; ++mt)
    #pragma unroll
    for (int nt = 0; nt < 4; ++nt)
      #pragma unroll
      for (int r = 0; r < 4; ++r)
        Sb[(size_t)(m0 + mt*16 + r0 + r)*CH + n0 + nt*16 + lr] = acc[mt][nt][r];
}

// ---------------- reduce partials: S[b] = sum_kc Sp[b][kc]
__global__ __launch_bounds__(256) void k_red(const float* __restrict__ Sp, float* __restrict__ S) {
  const int b = blockIdx.y;
  const size_t i = (size_t)blockIdx.x*256 + threadIdx.x;
  const float* p = Sp + (size_t)b*KC*CH*CH + i;
  float s = 0.f;
  #pragma unroll
  for (int kc = 0; kc < KC; ++kc) s += p[(size_t)kc*CH*CH];
  S[(size_t)b*CH*CH + i] = s;
}

// ---------------- k_vec2: s from psum; KS = KT^T s; Es = E s; qs = q.s  (per batch)
__global__ __launch_bounds__(256) void k_vec2(const float* __restrict__ psum,
    const float* __restrict__ E, const float* __restrict__ KT,
    const float* __restrict__ q, float* __restrict__ KS, float* __restrict__ Es,
    float* __restrict__ qs) {
  __shared__ float ls[CH];
  __shared__ float rbuf[4];
  const int b = blockIdx.x, t = threadIdx.x;
  float s = 0.f;
  for (int xb = 0; xb < 64; ++xb) s += psum[((size_t)b*64 + xb)*CH + t];
  ls[t] = s;
  __syncthreads();
  float ks = 0.f;
  for (int a = 0; a < CH; ++a) ks += KT[(size_t)a*CH + t] * ls[a];
  KS[(size_t)b*CH + t] = ks;
  float es = 0.f;
  for (int c = 0; c < CH; ++c) es += E[(size_t)t*CH + c] * ls[c];
  Es[(size_t)b*CH + t] = es;
  float p = q[t] * ls[t];
  #pragma unroll
  for (int o = 1; o < 64; o <<= 1) p += __shfl_xor(p, o, 64);
  if ((t & 63) == 0) rbuf[t >> 6] = p;
  __syncthreads();
  if (t == 0) qs[b] = rbuf[0] + rbuf[1] + rbuf[2] + rbuf[3];
}

// ---------------- k_R: R = E·S per batch (+Rq = R·q); grid (32,16), block 256
__global__ __launch_bounds__(256) void k_R(const float* __restrict__ S,
    const float* __restrict__ E, const float* __restrict__ q,
    float* __restrict__ R, float* __restrict__ Rq) {
  __shared__ float lEt[2048];
  __shared__ float red[32];
  const int b = blockIdx.y, o0 = blockIdx.x*8, t = threadIdx.x;
  #pragma unroll
  for (int k = 0; k < 8; ++k) { int idx = k*256 + t;
    lEt[idx] = E[(size_t)(o0 + (idx & 7))*CH + (idx >> 3)]; }
  __syncthreads();
  const float* Sb = S + (size_t)b*CH*CH;
  float acc[8] = {0.f};
  for (int c = 0; c < CH; ++c) {
    float sv = Sb[(size_t)c*CH + t];
    #pragma unroll
    for (int r = 0; r < 8; ++r) acc[r] += lEt[c*8 + r] * sv;
  }
  float* Rb = R + (size_t)b*CH*CH;
  #pragma unroll
  for (int r = 0; r < 8; ++r) Rb[(size_t)(o0 + r)*CH + t] = acc[r];
  const float qt = q[t];
  #pragma unroll
  for (int r = 0; r < 8; ++r) {
    float p = acc[r] * qt;
    #pragma unroll
    for (int o = 1; o < 64; o <<= 1) p += __shfl_xor(p, o, 64);
    if ((t & 63) == 0) red[r*4 + (t >> 6)] = p;
  }
  __syncthreads();
  if (t < 8) {
    float sum = red[t*4] + red[t*4+1] + red[t*4+2] + red[t*4+3];
    Rq[(size_t)b*CH + o0 + t] = sum;
  }
}

// ---------------- k_P: P = (inv/N)(R·KT + rank1s) -> bf16; also d vector
__global__ __launch_bounds__(256) void k_P(const float* __restrict__ R,
    const float* __restrict__ KT, const float* __restrict__ Rq,
    const float* __restrict__ KS, const float* __restrict__ Es,
    const float* __restrict__ qs, const float* __restrict__ wg,
    const float* __restrict__ tphi, const float* __restrict__ inv,
    const float* __restrict__ dconst, const float* __restrict__ tb,
    u16* __restrict__ Pb, float* __restrict__ dv) {
  __shared__ float lRt[2048];
  const int b = blockIdx.y, o0 = blockIdx.x*8, t = threadIdx.x;
  const float* Rb = R + (size_t)b*CH*CH;
  #pragma unroll
  for (int k = 0; k < 8; ++k) { int idx = k*256 + t;
    lRt[idx] = Rb[(size_t)(o0 + (idx & 7))*CH + (idx >> 3)]; }
  __syncthreads();
  float acc[8] = {0.f};
  for (int a = 0; a < CH; ++a) {
    float kv = KT[(size_t)a*CH + t];
    #pragma unroll
    for (int r = 0; r < 8; ++r) acc[r] += lRt[a*8 + r] * kv;
  }
  const float ksv = KS[(size_t)b*CH + t], tpv = tphi[t];
  u16* Pbb = Pb + (size_t)b*CH*CH;
  #pragma unroll
  for (int r = 0; r < 8; ++r) {
    int o = o0 + r;
    float val = (acc[r] + wg[o]*ksv + (Es[(size_t)b*CH + o] + (float)NSP*wg[o])*tpv)
                * inv[o] * (1.f/(float)NSP);
    Pbb[(size_t)o*CH + t] = f2b(val);
  }
  if (t < 8) {
    int o = o0 + t;
    float iv = inv[o], wgo = wg[o], tb0 = tb[0];
    float t2 = Rq[(size_t)b*CH + o] + wgo*qs[b] + Es[(size_t)b*CH + o]*tb0;
    dv[(size_t)b*CH + o] = iv*(t2*(1.f/(float)NSP) + wgo*tb0) + dconst[o];
  }
}

// ---------------- apply: out = X + P X + d 1^T  (LDS-staged B, 8 waves)
// grid (NSP/64, BATCH), block 512 (wave tile 32 rows x 64 cols)
__global__ __launch_bounds__(512, 4) void k_apply(const u16* __restrict__ Pb,
    const u16* __restrict__ xt, const float* __restrict__ x,
    const float* __restrict__ dv, float* __restrict__ out) {
  __shared__ u16 xs[64*256];     // 32 KB, XOR-swizzled 16B slots
  const int b = blockIdx.y, n0 = blockIdx.x*64;
  const int t = threadIdx.x, w = t >> 6, l = t & 63;
  {
    const u16* src = xt + ((size_t)b*NSP + n0)*CH;
    const int r = t >> 3, sbase = t & 7;
    #pragma unroll
    for (int it = 0; it < 4; ++it) {
      int slot = sbase + it*8;         // 0..31 (16B slots within 512B row)
      bf16x8 v = *(const bf16x8*)(src + (size_t)r*CH + slot*8);
      *(bf16x8*)(xs + r*256 + ((slot ^ (r & 7)) * 8)) = v;
    }
  }
  __syncthreads();
  const int m0 = w*32;
  const int lr = l & 15, lkb = l >> 4;   // k sub-block 0..3 (8 elems each)
  const int sw = lr & 7;
  const u16* Pp = Pb + (size_t)b*CH*CH;
  f32x4 acc[2][4];
  #pragma unroll
  for (int i = 0; i < 2; ++i)
    #pragma unroll
    for (int j = 0; j < 4; ++j) acc[i][j] = (f32x4){0.f,0.f,0.f,0.f};
  #pragma unroll
  for (int kk = 0; kk < 8; ++kk) {
    bf16x8 A[2], Bf[4];
    #pragma unroll
    for (int mt = 0; mt < 2; ++mt)
      A[mt] = *(const bf16x8*)(Pp + (size_t)(m0 + mt*16 + lr)*CH + kk*32 + lkb*8);
    #pragma unroll
    for (int nt = 0; nt < 4; ++nt) {
      int slot = kk*4 + lkb;
      Bf[nt] = *(const bf16x8*)(xs + (nt*16 + lr)*256 + ((slot ^ sw) * 8));
    }
    #pragma unroll
    for (int mt = 0; mt < 2; ++mt)
      #pragma unroll
      for (int nt = 0; nt < 4; ++nt)
        acc[mt][nt] = __builtin_amdgcn_mfma_f32_16x16x32_bf16(A[mt], Bf[nt], acc[mt][nt], 0, 0, 0);
  }
  const float* xpb = x + (size_t)b*CH*NSP;
  float* ob = out + (size_t)b*CH*NSP;
  const int r0 = (l >> 4) * 4;
  #pragma unroll
  for (int mt = 0; mt < 2; ++mt)
    #pragma unroll
    for (int rr = 0; rr < 4; ++rr) {
      int row = m0 + mt*16 + r0 + rr;
      float dval = dv[(size_t)b*CH + row];
      #pragma unroll
      for (int nt = 0; nt < 4; ++nt) {
        int col = n0 + nt*16 + lr;
        ob[(size_t)row*NSP + col] = acc[mt][nt][rr] + xpb[(size_t)row*NSP + col] + dval;
      }
    }
}

// ---------------- workspace layout (bytes)
static constexpr size_t XT_OFF = 0;              // bf16 [16][4096][256]  33,554,432
static constexpr size_t S_OFF  = 33554432;       // f32  [16][256][256]    4,194,304
static constexpr size_t PB_OFF = 37748736;       // bf16 [16][256][256]    2,097,152
static constexpr size_t PS_OFF = 39845888;       // f32  [16][64][256]     1,048,576
static constexpr size_t E_OFF  = 40894464;       // f32  [256][256]          262,144
static constexpr size_t KT_OFF = 41156608;       // f32  [256][256]          262,144
static constexpr size_t WG_OFF = 41418752;       // f32 [256] (1K pad each follows)
static constexpr size_t TP_OFF = 41419776;
static constexpr size_t QV_OFF = 41420800;
static constexpr size_t IV_OFF = 41421824;
static constexpr size_t DC_OFF = 41422848;
static constexpr size_t TB_OFF = 41423872;
static constexpr size_t KS_OFF = 41424896;       // f32 [16][256] 16,384
static constexpr size_t ES_OFF = 41441280;       // f32 [16][256] 16,384
static constexpr size_t RQ_OFF = 41457664;       // f32 [16][256] 16,384
static constexpr size_t QS_OFF = 41474048;       // f32 [16] (1K pad)
static constexpr size_t DV_OFF = 41475072;       // f32 [16][256] 16,384

extern "C" void kernel_launch(void* const* d_in, const int* in_sizes, int n_in,
                              void* d_out, int out_size, void* d_ws, size_t ws_size,
                              hipStream_t stream) {
  const float* x       = (const float*)d_in[0];
  const float* g_w     = (const float*)d_in[1];
  const float* g_b     = (const float*)d_in[2];
  const float* theta_w = (const float*)d_in[3];
  const float* theta_b = (const float*)d_in[4];
  const float* phi_w   = (const float*)d_in[5];
  const float* phi_b   = (const float*)d_in[6];
  const float* w_w     = (const float*)d_in[7];
  const float* w_b     = (const float*)d_in[8];
  const float* bn_g    = (const float*)d_in[9];
  const float* bn_b    = (const float*)d_in[10];
  const float* bn_m    = (const float*)d_in[11];
  const float* bn_v    = (const float*)d_in[12];
  float* out = (float*)d_out;
  char* ws = (char*)d_ws;
  u16*   XT = (u16*)(ws + XT_OFF);
  float* S  = (float*)(ws + S_OFF);
  u16*   Pb = (u16*)(ws + PB_OFF);
  float* PS = (float*)(ws + PS_OFF);
  float* E  = (float*)(ws + E_OFF);
  float* KT = (float*)(ws + KT_OFF);
  float* WG = (float*)(ws + WG_OFF);
  float* TP = (float*)(ws + TP_OFF);
  float* QV = (float*)(ws + QV_OFF);
  float* IV = (float*)(ws + IV_OFF);
  float* DC = (float*)(ws + DC_OFF);
  float* TB = (float*)(ws + TB_OFF);
  float* KS = (float*)(ws + KS_OFF);
  float* ES = (float*)(ws + ES_OFF);
  float* RQ = (float*)(ws + RQ_OFF);
  float* QS = (float*)(ws + QS_OFF);
  float* DV = (float*)(ws + DV_OFF);
  // d_out scratch: Xb bf16 [0, 33.5MB); Sp partials [33.5MB, 67MB); R overlays dead Sp.
  // All dead before k_apply rewrites d_out.
  u16*   Xb = (u16*)d_out;
  float* Sp = (float*)((char*)d_out + 33554432);
  float* R  = (float*)((char*)d_out + 33554432);

  k_const<<<dim3(65),                    256, 0, stream>>>(w_w, g_w, g_b, theta_w, theta_b,
                                                           phi_w, phi_b, w_b, bn_g, bn_b, bn_m, bn_v,
                                                           E, KT, WG, TP, QV, IV, DC, TB);
  k_prep <<<dim3(NSP/64, CH/64, BATCH),  256, 0, stream>>>(x, Xb, XT, PS);
  k_gram <<<dim3(2, 2, BATCH*KC),        512, 0, stream>>>(Xb, Sp);
  k_red  <<<dim3(CH*CH/256, BATCH),      256, 0, stream>>>(Sp, S);
  k_vec2 <<<dim3(BATCH),                 256, 0, stream>>>(PS, E, KT, QV, KS, ES, QS);
  k_R    <<<dim3(32, BATCH),             256, 0, stream>>>(S, E, QV, R, RQ);
  k_P    <<<dim3(32, BATCH),             256, 0, stream>>>(R, KT, RQ, KS, ES, QS, WG, TP, IV, DC, TB, Pb, DV);
  k_apply<<<dim3(NSP/64, BATCH),         512, 0, stream>>>(Pb, XT, x, DV, out);
}

// Round 4
// 142.591 us; speedup vs baseline: 2.3930x; 1.2423x over previous
//
#include <hip/hip_runtime.h>
#include <stdint.h>

#define BATCH 16
#define CH    256
#define CI    128
#define NSP   4096
#define KC    8          // K-split chunks for the Gram GEMM
#define EPSV  1e-5f

typedef unsigned short u16;
typedef __attribute__((ext_vector_type(4))) float f32x4;
typedef __attribute__((ext_vector_type(8))) short bf16x8;

__device__ __forceinline__ u16 f2b(float f) {
  uint32_t u = __float_as_uint(f);
  uint32_t r = u + 0x7FFFu + ((u >> 16) & 1u);   // round-to-nearest-even
  return (u16)(r >> 16);
}

__device__ __forceinline__ void async16(void* lds, const void* g) {
  __builtin_amdgcn_global_load_lds(
      (const __attribute__((address_space(1))) unsigned int*)g,
      (__attribute__((address_space(3))) unsigned int*)lds, 16, 0, 0);
}

// ---------------- k_const: batch-independent matrices/vectors
__global__ __launch_bounds__(256) void k_const(const float* __restrict__ w_w,
    const float* __restrict__ g_w, const float* __restrict__ g_b,
    const float* __restrict__ theta_w, const float* __restrict__ theta_b,
    const float* __restrict__ phi_w, const float* __restrict__ phi_b,
    const float* __restrict__ w_b, const float* __restrict__ bn_g,
    const float* __restrict__ bn_b, const float* __restrict__ bn_m,
    const float* __restrict__ bn_v,
    float* __restrict__ E, float* __restrict__ KT, float* __restrict__ wg,
    float* __restrict__ tphi, float* __restrict__ q, float* __restrict__ inv,
    float* __restrict__ dconst, float* __restrict__ tb) {
  __shared__ float lbuf[1024];
  const int blk = blockIdx.x, t = threadIdx.x;
  if (blk < 32) {                 // E rows o0..o0+7
    const int o0 = blk*8;
    #pragma unroll
    for (int k = 0; k < 4; ++k) { int idx = k*256 + t;
      lbuf[idx] = w_w[(size_t)(o0 + (idx & 7))*CI + (idx >> 3)]; }
    __syncthreads();
    float acc[8] = {0.f};
    for (int j = 0; j < CI; ++j) {
      float gv = g_w[(size_t)j*CH + t];
      #pragma unroll
      for (int r = 0; r < 8; ++r) acc[r] += lbuf[j*8 + r] * gv;
    }
    #pragma unroll
    for (int r = 0; r < 8; ++r) E[(size_t)(o0 + r)*CH + t] = acc[r];
  } else if (blk < 64) {          // KT rows a0..a0+7
    const int a0 = (blk - 32)*8;
    #pragma unroll
    for (int k = 0; k < 4; ++k) { int idx = k*256 + t;
      lbuf[idx] = phi_w[(size_t)(idx >> 3)*CH + a0 + (idx & 7)]; }
    __syncthreads();
    float acc[8] = {0.f};
    for (int i = 0; i < CI; ++i) {
      float tv = theta_w[(size_t)i*CH + t];
      #pragma unroll
      for (int u = 0; u < 8; ++u) acc[u] += lbuf[i*8 + u] * tv;
    }
    #pragma unroll
    for (int u = 0; u < 8; ++u) KT[(size_t)(a0 + u)*CH + t] = acc[u];
  } else {                        // vectors
    float iv = bn_g[t] * rsqrtf(bn_v[t] + EPSV);
    inv[t] = iv;
    dconst[t] = iv*w_b[t] + bn_b[t] - bn_m[t]*iv;
    float a = 0.f;
    for (int j = 0; j < CI; ++j) a += w_w[(size_t)t*CI + j] * g_b[j];
    wg[t] = a;
    float tp = 0.f, qq = 0.f;
    for (int i = 0; i < CI; ++i) {
      tp += theta_w[(size_t)i*CH + t] * phi_b[i];
      qq += phi_w[(size_t)i*CH + t] * theta_b[i];
    }
    tphi[t] = tp; q[t] = qq;
    lbuf[t] = (t < CI) ? theta_b[t]*phi_b[t] : 0.f;
    __syncthreads();
    for (int s2 = 128; s2 > 0; s2 >>= 1) { if (t < s2) lbuf[t] += lbuf[t + s2]; __syncthreads(); }
    if (t == 0) tb[0] = lbuf[0];
  }
}

// ---------------- kernel 1: bf16 convert (row-major + transposed) + row-sum partials
__global__ __launch_bounds__(256) void k_prep(const float* __restrict__ x,
    u16* __restrict__ xb, u16* __restrict__ xt, float* __restrict__ psum) {
  __shared__ float tile[64*64];
  const int b = blockIdx.z, c0 = blockIdx.y*64, n0 = blockIdx.x*64;
  const int t = threadIdx.x;
  const int lane16 = t & 15;
  const int grp = t >> 4;              // 0..15
  const float* xp = x + ((size_t)b*CH + c0)*NSP + n0;
  u16* xbp = xb + ((size_t)b*CH + c0)*NSP + n0;
  #pragma unroll
  for (int p = 0; p < 4; ++p) {
    int cl = grp + p*16;               // row within tile, 0..63
    int nl = lane16*4;
    float4 v = *(const float4*)(xp + (size_t)cl*NSP + nl);
    float ps = v.x + v.y + v.z + v.w;
    #pragma unroll
    for (int o = 1; o < 16; o <<= 1) ps += __shfl_xor(ps, o, 64);
    if (lane16 == 0) psum[((size_t)b*64 + blockIdx.x)*CH + c0 + cl] = ps;
    ushort4 bv; bv.x=f2b(v.x); bv.y=f2b(v.y); bv.z=f2b(v.z); bv.w=f2b(v.w);
    *(ushort4*)(xbp + (size_t)cl*NSP + nl) = bv;
    float vv[4] = {v.x, v.y, v.z, v.w};
    #pragma unroll
    for (int j = 0; j < 4; ++j) {
      int n = nl + j;
      tile[n*64 + (cl ^ (((n>>2)&7)<<2))] = vv[j];
    }
  }
  __syncthreads();
  u16* xtp = xt + ((size_t)b*NSP + n0)*CH + c0;
  #pragma unroll
  for (int q2 = 0; q2 < 4; ++q2) {
    int nl = grp + q2*16;
    int c4 = lane16*4;
    float4 v = *(const float4*)&tile[nl*64 + (c4 ^ (((nl>>2)&7)<<2))];
    ushort4 bv; bv.x=f2b(v.x); bv.y=f2b(v.y); bv.z=f2b(v.z); bv.w=f2b(v.w);
    *(ushort4*)(xtp + (size_t)nl*CH + c4) = bv;
  }
}

// ---------------- kernel 2: Gram partials, LDS-staged (m97 structure) + symmetry
// 384 blocks (XCD-swizzled): (b, kc, q) with q in {(0,0),(0,1),(1,1)}.
// Block 256 thr = 4 waves, wave tile 64x64, BK=64, single-buffer 2-barrier loop.
// LDS dest linear; global src pre-swizzled (slot ^ (row&7)) for conflict-free ds_read_b128.
__global__ __launch_bounds__(256) void k_gram(const u16* __restrict__ xb, float* __restrict__ Sp) {
  __shared__ u16 As[128*64];   // 16 KB
  __shared__ u16 Bs[128*64];   // 16 KB
  const int L = blockIdx.x;
  const int wk = (L & 7) * 48 + (L >> 3);   // bijective: 384 = 8*48, clusters 2 batches/XCD
  const int b = wk / 24;
  const int rem = wk % 24;
  const int kc = rem / 3;
  const int q = rem % 3;                    // 0:(0,0) 1:(0,1) 2:(1,1)
  const int m_base = (q == 2) ? 128 : 0;
  const int n_base = (q == 0) ? 0 : 128;
  const int t = threadIdx.x, wv = t >> 6, l = t & 63;
  const int wr = wv >> 1, wc = wv & 1;
  const int lr = l & 15, lkb = l >> 4;      // fragment row lane, k sub-block
  const int sr = l >> 3, ss = l & 7;        // staging: row-within-8, slot
  const u16* xa = xb + (size_t)b*CH*NSP;
  const int kbeg = kc * (NSP/KC);
  f32x4 acc[4][4];
  #pragma unroll
  for (int i = 0; i < 4; ++i)
    #pragma unroll
    for (int j = 0; j < 4; ++j) acc[i][j] = (f32x4){0.f,0.f,0.f,0.f};

  for (int kk = 0; kk < 8; ++kk) {
    const int kpos = kbeg + kk*64;
    // stage A (and B if off-diagonal): 16 instrs of 1KB each, 4 per wave
    #pragma unroll
    for (int j4 = 0; j4 < 4; ++j4) {
      const int j = wv*4 + j4;
      const int r = j*8 + sr;               // 0..127
      async16(&As[j*512], xa + (size_t)(m_base + r)*NSP + kpos + ((ss ^ (r & 7)) * 8));
    }
    if (q == 1) {
      #pragma unroll
      for (int j4 = 0; j4 < 4; ++j4) {
        const int j = wv*4 + j4;
        const int r = j*8 + sr;
        async16(&Bs[j*512], xa + (size_t)(n_base + r)*NSP + kpos + ((ss ^ (r & 7)) * 8));
      }
    }
    __syncthreads();
    const u16* bsrc = (q == 1) ? Bs : As;
    #pragma unroll
    for (int ks = 0; ks < 2; ++ks) {
      bf16x8 A[4], Bf[4];
      #pragma unroll
      for (int mt = 0; mt < 4; ++mt) {
        const int ra = wr*64 + mt*16 + lr;
        A[mt] = *(const bf16x8*)(As + ra*64 + (((ks*4 + lkb) ^ (ra & 7)) * 8));
      }
      #pragma unroll
      for (int nt = 0; nt < 4; ++nt) {
        const int rb = wc*64 + nt*16 + lr;
        Bf[nt] = *(const bf16x8*)(bsrc + rb*64 + (((ks*4 + lkb) ^ (rb & 7)) * 8));
      }
      #pragma unroll
      for (int mt = 0; mt < 4; ++mt)
        #pragma unroll
        for (int nt = 0; nt < 4; ++nt)
          acc[mt][nt] = __builtin_amdgcn_mfma_f32_16x16x32_bf16(A[mt], Bf[nt], acc[mt][nt], 0, 0, 0);
    }
    __syncthreads();
  }
  float* Sb = Sp + (size_t)(b*KC + kc)*CH*CH;
  const int r0 = (l >> 4) * 4;
  #pragma unroll
  for (int mt = 0; mt < 4; ++mt)
    #pragma unroll
    for (int nt = 0; nt < 4; ++nt)
      #pragma unroll
      for (int rr = 0; rr < 4; ++rr)
        Sb[(size_t)(m_base + wr*64 + mt*16 + r0 + rr)*CH + n_base + wc*64 + nt*16 + lr]
          = acc[mt][nt][rr];
}

// ---------------- reduce partials with symmetric fill
// grid (12, BATCH): 12 64x64 tiles over quadrants (0,0),(0,1),(1,1); (1,0) = (0,1)^T
__global__ __launch_bounds__(256) void k_red(const float* __restrict__ Sp, float* __restrict__ S) {
  __shared__ float tl[64*65];
  const int b = blockIdx.y, tt = blockIdx.x, t = threadIdx.x;
  const int qq = tt >> 2, sub = tt & 3;
  const int qi = (qq == 2) ? 1 : 0, qj = (qq == 0) ? 0 : 1;
  const int row0 = qi*128 + (sub >> 1)*64, col0 = qj*128 + (sub & 1)*64;
  const float* p = Sp + (size_t)b*KC*CH*CH;
  float* Sb = S + (size_t)b*CH*CH;
  float4 sum[4];
  #pragma unroll
  for (int k = 0; k < 4; ++k) {
    const int slot = t + k*256;                 // float4 slot in 64x64 tile
    const int r = slot >> 4, c4 = (slot & 15) * 4;
    float4 s = {0.f,0.f,0.f,0.f};
    #pragma unroll
    for (int kc = 0; kc < KC; ++kc) {
      float4 v = *(const float4*)(p + (size_t)kc*CH*CH + (size_t)(row0 + r)*CH + col0 + c4);
      s.x += v.x; s.y += v.y; s.z += v.z; s.w += v.w;
    }
    sum[k] = s;
    *(float4*)(Sb + (size_t)(row0 + r)*CH + col0 + c4) = s;
  }
  if (qq == 1) {                                // mirror to (1,0)
    #pragma unroll
    for (int k = 0; k < 4; ++k) {
      const int slot = t + k*256;
      const int r = slot >> 4, c4 = (slot & 15) * 4;
      tl[r*65 + c4+0] = sum[k].x; tl[r*65 + c4+1] = sum[k].y;
      tl[r*65 + c4+2] = sum[k].z; tl[r*65 + c4+3] = sum[k].w;
    }
    __syncthreads();
    #pragma unroll
    for (int k = 0; k < 4; ++k) {
      const int slot = t + k*256;
      const int r = slot >> 4, c4 = (slot & 15) * 4;   // row/cols of TRANSPOSED tile
      float4 v = { tl[(c4+0)*65 + r], tl[(c4+1)*65 + r], tl[(c4+2)*65 + r], tl[(c4+3)*65 + r] };
      *(float4*)(Sb + (size_t)(col0 + r)*CH + row0 + c4) = v;
    }
  }
}

// ---------------- k_vec2: s from psum; KS = KT^T s; Es = E s; qs = q.s  (per batch)
__global__ __launch_bounds__(256) void k_vec2(const float* __restrict__ psum,
    const float* __restrict__ E, const float* __restrict__ KT,
    const float* __restrict__ q, float* __restrict__ KS, float* __restrict__ Es,
    float* __restrict__ qs) {
  __shared__ float ls[CH];
  __shared__ float rbuf[4];
  const int b = blockIdx.x, t = threadIdx.x;
  float s = 0.f;
  for (int xb = 0; xb < 64; ++xb) s += psum[((size_t)b*64 + xb)*CH + t];
  ls[t] = s;
  __syncthreads();
  float ks = 0.f;
  for (int a = 0; a < CH; ++a) ks += KT[(size_t)a*CH + t] * ls[a];
  KS[(size_t)b*CH + t] = ks;
  float es = 0.f;
  for (int c = 0; c < CH; ++c) es += E[(size_t)t*CH + c] * ls[c];
  Es[(size_t)b*CH + t] = es;
  float p = q[t] * ls[t];
  #pragma unroll
  for (int o = 1; o < 64; o <<= 1) p += __shfl_xor(p, o, 64);
  if ((t & 63) == 0) rbuf[t >> 6] = p;
  __syncthreads();
  if (t == 0) qs[b] = rbuf[0] + rbuf[1] + rbuf[2] + rbuf[3];
}

// ---------------- k_R: R = E·S per batch (+Rq = R·q); grid (32,16), block 256
__global__ __launch_bounds__(256) void k_R(const float* __restrict__ S,
    const float* __restrict__ E, const float* __restrict__ q,
    float* __restrict__ R, float* __restrict__ Rq) {
  __shared__ float lEt[2048];
  __shared__ float red[32];
  const int b = blockIdx.y, o0 = blockIdx.x*8, t = threadIdx.x;
  #pragma unroll
  for (int k = 0; k < 8; ++k) { int idx = k*256 + t;
    lEt[idx] = E[(size_t)(o0 + (idx & 7))*CH + (idx >> 3)]; }
  __syncthreads();
  const float* Sb = S + (size_t)b*CH*CH;
  float acc[8] = {0.f};
  for (int c = 0; c < CH; ++c) {
    float sv = Sb[(size_t)c*CH + t];
    #pragma unroll
    for (int r = 0; r < 8; ++r) acc[r] += lEt[c*8 + r] * sv;
  }
  float* Rb = R + (size_t)b*CH*CH;
  #pragma unroll
  for (int r = 0; r < 8; ++r) Rb[(size_t)(o0 + r)*CH + t] = acc[r];
  const float qt = q[t];
  #pragma unroll
  for (int r = 0; r < 8; ++r) {
    float p = acc[r] * qt;
    #pragma unroll
    for (int o = 1; o < 64; o <<= 1) p += __shfl_xor(p, o, 64);
    if ((t & 63) == 0) red[r*4 + (t >> 6)] = p;
  }
  __syncthreads();
  if (t < 8) {
    float sum = red[t*4] + red[t*4+1] + red[t*4+2] + red[t*4+3];
    Rq[(size_t)b*CH + o0 + t] = sum;
  }
}

// ---------------- k_P: P = (inv/N)(R·KT + rank1s) -> bf16; also d vector
__global__ __launch_bounds__(256) void k_P(const float* __restrict__ R,
    const float* __restrict__ KT, const float* __restrict__ Rq,
    const float* __restrict__ KS, const float* __restrict__ Es,
    const float* __restrict__ qs, const float* __restrict__ wg,
    const float* __restrict__ tphi, const float* __restrict__ inv,
    const float* __restrict__ dconst, const float* __restrict__ tb,
    u16* __restrict__ Pb, float* __restrict__ dv) {
  __shared__ float lRt[2048];
  const int b = blockIdx.y, o0 = blockIdx.x*8, t = threadIdx.x;
  const float* Rb = R + (size_t)b*CH*CH;
  #pragma unroll
  for (int k = 0; k < 8; ++k) { int idx = k*256 + t;
    lRt[idx] = Rb[(size_t)(o0 + (idx & 7))*CH + (idx >> 3)]; }
  __syncthreads();
  float acc[8] = {0.f};
  for (int a = 0; a < CH; ++a) {
    float kv = KT[(size_t)a*CH + t];
    #pragma unroll
    for (int r = 0; r < 8; ++r) acc[r] += lRt[a*8 + r] * kv;
  }
  const float ksv = KS[(size_t)b*CH + t], tpv = tphi[t];
  u16* Pbb = Pb + (size_t)b*CH*CH;
  #pragma unroll
  for (int r = 0; r < 8; ++r) {
    int o = o0 + r;
    float val = (acc[r] + wg[o]*ksv + (Es[(size_t)b*CH + o] + (float)NSP*wg[o])*tpv)
                * inv[o] * (1.f/(float)NSP);
    Pbb[(size_t)o*CH + t] = f2b(val);
  }
  if (t < 8) {
    int o = o0 + t;
    float iv = inv[o], wgo = wg[o], tb0 = tb[0];
    float t2 = Rq[(size_t)b*CH + o] + wgo*qs[b] + Es[(size_t)b*CH + o]*tb0;
    dv[(size_t)b*CH + o] = iv*(t2*(1.f/(float)NSP) + wgo*tb0) + dconst[o];
  }
}

// ---------------- apply: out = X + P X + d 1^T  (LDS-staged B, 8 waves)
__global__ __launch_bounds__(512, 4) void k_apply(const u16* __restrict__ Pb,
    const u16* __restrict__ xt, const float* __restrict__ x,
    const float* __restrict__ dv, float* __restrict__ out) {
  __shared__ u16 xs[64*256];     // 32 KB, XOR-swizzled 16B slots
  const int b = blockIdx.y, n0 = blockIdx.x*64;
  const int t = threadIdx.x, w = t >> 6, l = t & 63;
  {
    const u16* src = xt + ((size_t)b*NSP + n0)*CH;
    const int r = t >> 3, sbase = t & 7;
    #pragma unroll
    for (int it = 0; it < 4; ++it) {
      int slot = sbase + it*8;         // 0..31 (16B slots within 512B row)
      bf16x8 v = *(const bf16x8*)(src + (size_t)r*CH + slot*8);
      *(bf16x8*)(xs + r*256 + ((slot ^ (r & 7)) * 8)) = v;
    }
  }
  __syncthreads();
  const int m0 = w*32;
  const int lr = l & 15, lkb = l >> 4;   // k sub-block 0..3 (8 elems each)
  const int sw = lr & 7;
  const u16* Pp = Pb + (size_t)b*CH*CH;
  f32x4 acc[2][4];
  #pragma unroll
  for (int i = 0; i < 2; ++i)
    #pragma unroll
    for (int j = 0; j < 4; ++j) acc[i][j] = (f32x4){0.f,0.f,0.f,0.f};
  #pragma unroll
  for (int kk = 0; kk < 8; ++kk) {
    bf16x8 A[2], Bf[4];
    #pragma unroll
    for (int mt = 0; mt < 2; ++mt)
      A[mt] = *(const bf16x8*)(Pp + (size_t)(m0 + mt*16 + lr)*CH + kk*32 + lkb*8);
    #pragma unroll
    for (int nt = 0; nt < 4; ++nt) {
      int slot = kk*4 + lkb;
      Bf[nt] = *(const bf16x8*)(xs + (nt*16 + lr)*256 + ((slot ^ sw) * 8));
    }
    #pragma unroll
    for (int mt = 0; mt < 2; ++mt)
      #pragma unroll
      for (int nt = 0; nt < 4; ++nt)
        acc[mt][nt] = __builtin_amdgcn_mfma_f32_16x16x32_bf16(A[mt], Bf[nt], acc[mt][nt], 0, 0, 0);
  }
  const float* xpb = x + (size_t)b*CH*NSP;
  float* ob = out + (size_t)b*CH*NSP;
  const int r0 = (l >> 4) * 4;
  #pragma unroll
  for (int mt = 0; mt < 2; ++mt)
    #pragma unroll
    for (int rr = 0; rr < 4; ++rr) {
      int row = m0 + mt*16 + r0 + rr;
      float dval = dv[(size_t)b*CH + row];
      #pragma unroll
      for (int nt = 0; nt < 4; ++nt) {
        int col = n0 + nt*16 + lr;
        ob[(size_t)row*NSP + col] = acc[mt][nt][rr] + xpb[(size_t)row*NSP + col] + dval;
      }
    }
}

// ---------------- workspace layout (bytes)
static constexpr size_t XT_OFF = 0;              // bf16 [16][4096][256]  33,554,432
static constexpr size_t S_OFF  = 33554432;       // f32  [16][256][256]    4,194,304
static constexpr size_t PB_OFF = 37748736;       // bf16 [16][256][256]    2,097,152
static constexpr size_t PS_OFF = 39845888;       // f32  [16][64][256]     1,048,576
static constexpr size_t E_OFF  = 40894464;       // f32  [256][256]          262,144
static constexpr size_t KT_OFF = 41156608;       // f32  [256][256]          262,144
static constexpr size_t WG_OFF = 41418752;       // f32 [256] (1K pad each follows)
static constexpr size_t TP_OFF = 41419776;
static constexpr size_t QV_OFF = 41420800;
static constexpr size_t IV_OFF = 41421824;
static constexpr size_t DC_OFF = 41422848;
static constexpr size_t TB_OFF = 41423872;
static constexpr size_t KS_OFF = 41424896;       // f32 [16][256] 16,384
static constexpr size_t ES_OFF = 41441280;       // f32 [16][256] 16,384
static constexpr size_t RQ_OFF = 41457664;       // f32 [16][256] 16,384
static constexpr size_t QS_OFF = 41474048;       // f32 [16] (1K pad)
static constexpr size_t DV_OFF = 41475072;       // f32 [16][256] 16,384

extern "C" void kernel_launch(void* const* d_in, const int* in_sizes, int n_in,
                              void* d_out, int out_size, void* d_ws, size_t ws_size,
                              hipStream_t stream) {
  const float* x       = (const float*)d_in[0];
  const float* g_w     = (const float*)d_in[1];
  const float* g_b     = (const float*)d_in[2];
  const float* theta_w = (const float*)d_in[3];
  const float* theta_b = (const float*)d_in[4];
  const float* phi_w   = (const float*)d_in[5];
  const float* phi_b   = (const float*)d_in[6];
  const float* w_w     = (const float*)d_in[7];
  const float* w_b     = (const float*)d_in[8];
  const float* bn_g    = (const float*)d_in[9];
  const float* bn_b    = (const float*)d_in[10];
  const float* bn_m    = (const float*)d_in[11];
  const float* bn_v    = (const float*)d_in[12];
  float* out = (float*)d_out;
  char* ws = (char*)d_ws;
  u16*   XT = (u16*)(ws + XT_OFF);
  float* S  = (float*)(ws + S_OFF);
  u16*   Pb = (u16*)(ws + PB_OFF);
  float* PS = (float*)(ws + PS_OFF);
  float* E  = (float*)(ws + E_OFF);
  float* KT = (float*)(ws + KT_OFF);
  float* WG = (float*)(ws + WG_OFF);
  float* TP = (float*)(ws + TP_OFF);
  float* QV = (float*)(ws + QV_OFF);
  float* IV = (float*)(ws + IV_OFF);
  float* DC = (float*)(ws + DC_OFF);
  float* TB = (float*)(ws + TB_OFF);
  float* KS = (float*)(ws + KS_OFF);
  float* ES = (float*)(ws + ES_OFF);
  float* RQ = (float*)(ws + RQ_OFF);
  float* QS = (float*)(ws + QS_OFF);
  float* DV = (float*)(ws + DV_OFF);
  // d_out scratch: Xb bf16 [0, 33.5MB); Sp partials [33.5MB, 67MB); R overlays dead Sp.
  u16*   Xb = (u16*)d_out;
  float* Sp = (float*)((char*)d_out + 33554432);
  float* R  = (float*)((char*)d_out + 33554432);

  k_const<<<dim3(65),                    256, 0, stream>>>(w_w, g_w, g_b, theta_w, theta_b,
                                                           phi_w, phi_b, w_b, bn_g, bn_b, bn_m, bn_v,
                                                           E, KT, WG, TP, QV, IV, DC, TB);
  k_prep <<<dim3(NSP/64, CH/64, BATCH),  256, 0, stream>>>(x, Xb, XT, PS);
  k_gram <<<dim3(384),                   256, 0, stream>>>(Xb, Sp);
  k_red  <<<dim3(12, BATCH),             256, 0, stream>>>(Sp, S);
  k_vec2 <<<dim3(BATCH),                 256, 0, stream>>>(PS, E, KT, QV, KS, ES, QS);
  k_R    <<<dim3(32, BATCH),             256, 0, stream>>>(S, E, QV, R, RQ);
  k_P    <<<dim3(32, BATCH),             256, 0, stream>>>(R, KT, RQ, KS, ES, QS, WG, TP, IV, DC, TB, Pb, DV);
  k_apply<<<dim3(NSP/64, BATCH),         512, 0, stream>>>(Pb, XT, x, DV, out);
}

// Round 5
// 136.392 us; speedup vs baseline: 2.5017x; 1.0454x over previous
//
#include <hip/hip_runtime.h>
#include <stdint.h>

#define BATCH 16
#define CH    256
#define CI    128
#define NSP   4096
#define KC    8          // K-split chunks for the Gram GEMM
#define EPSV  1e-5f

typedef unsigned short u16;
typedef __attribute__((ext_vector_type(4))) float f32x4;
typedef __attribute__((ext_vector_type(8))) short bf16x8;

__device__ __forceinline__ u16 f2b(float f) {
  uint32_t u = __float_as_uint(f);
  uint32_t r = u + 0x7FFFu + ((u >> 16) & 1u);   // round-to-nearest-even
  return (u16)(r >> 16);
}

__device__ __forceinline__ void async16(void* lds, const void* g) {
  __builtin_amdgcn_global_load_lds(
      (const __attribute__((address_space(1))) unsigned int*)g,
      (__attribute__((address_space(3))) unsigned int*)lds, 16, 0, 0);
}

// ---------------- k_const: batch-independent matrices/vectors
__global__ __launch_bounds__(256) void k_const(const float* __restrict__ w_w,
    const float* __restrict__ g_w, const float* __restrict__ g_b,
    const float* __restrict__ theta_w, const float* __restrict__ theta_b,
    const float* __restrict__ phi_w, const float* __restrict__ phi_b,
    const float* __restrict__ w_b, const float* __restrict__ bn_g,
    const float* __restrict__ bn_b, const float* __restrict__ bn_m,
    const float* __restrict__ bn_v,
    float* __restrict__ E, float* __restrict__ KT, float* __restrict__ wg,
    float* __restrict__ tphi, float* __restrict__ q, float* __restrict__ inv,
    float* __restrict__ dconst, float* __restrict__ tb) {
  __shared__ float lbuf[1024];
  const int blk = blockIdx.x, t = threadIdx.x;
  if (blk < 32) {                 // E rows o0..o0+7
    const int o0 = blk*8;
    #pragma unroll
    for (int k = 0; k < 4; ++k) { int idx = k*256 + t;
      lbuf[idx] = w_w[(size_t)(o0 + (idx & 7))*CI + (idx >> 3)]; }
    __syncthreads();
    float acc[8] = {0.f};
    for (int j = 0; j < CI; ++j) {
      float gv = g_w[(size_t)j*CH + t];
      #pragma unroll
      for (int r = 0; r < 8; ++r) acc[r] += lbuf[j*8 + r] * gv;
    }
    #pragma unroll
    for (int r = 0; r < 8; ++r) E[(size_t)(o0 + r)*CH + t] = acc[r];
  } else if (blk < 64) {          // KT rows a0..a0+7
    const int a0 = (blk - 32)*8;
    #pragma unroll
    for (int k = 0; k < 4; ++k) { int idx = k*256 + t;
      lbuf[idx] = phi_w[(size_t)(idx >> 3)*CH + a0 + (idx & 7)]; }
    __syncthreads();
    float acc[8] = {0.f};
    for (int i = 0; i < CI; ++i) {
      float tv = theta_w[(size_t)i*CH + t];
      #pragma unroll
      for (int u = 0; u < 8; ++u) acc[u] += lbuf[i*8 + u] * tv;
    }
    #pragma unroll
    for (int u = 0; u < 8; ++u) KT[(size_t)(a0 + u)*CH + t] = acc[u];
  } else {                        // vectors
    float iv = bn_g[t] * rsqrtf(bn_v[t] + EPSV);
    inv[t] = iv;
    dconst[t] = iv*w_b[t] + bn_b[t] - bn_m[t]*iv;
    float a = 0.f;
    for (int j = 0; j < CI; ++j) a += w_w[(size_t)t*CI + j] * g_b[j];
    wg[t] = a;
    float tp = 0.f, qq = 0.f;
    for (int i = 0; i < CI; ++i) {
      tp += theta_w[(size_t)i*CH + t] * phi_b[i];
      qq += phi_w[(size_t)i*CH + t] * theta_b[i];
    }
    tphi[t] = tp; q[t] = qq;
    lbuf[t] = (t < CI) ? theta_b[t]*phi_b[t] : 0.f;
    __syncthreads();
    for (int s2 = 128; s2 > 0; s2 >>= 1) { if (t < s2) lbuf[t] += lbuf[t + s2]; __syncthreads(); }
    if (t == 0) tb[0] = lbuf[0];
  }
}

// ---------------- kernel 1: bf16 convert (row-major + transposed) + row-sum partials
__global__ __launch_bounds__(256) void k_prep(const float* __restrict__ x,
    u16* __restrict__ xb, u16* __restrict__ xt, float* __restrict__ psum) {
  __shared__ float tile[64*64];
  const int b = blockIdx.z, c0 = blockIdx.y*64, n0 = blockIdx.x*64;
  const int t = threadIdx.x;
  const int lane16 = t & 15;
  const int grp = t >> 4;              // 0..15
  const float* xp = x + ((size_t)b*CH + c0)*NSP + n0;
  u16* xbp = xb + ((size_t)b*CH + c0)*NSP + n0;
  #pragma unroll
  for (int p = 0; p < 4; ++p) {
    int cl = grp + p*16;               // row within tile, 0..63
    int nl = lane16*4;
    float4 v = *(const float4*)(xp + (size_t)cl*NSP + nl);
    float ps = v.x + v.y + v.z + v.w;
    #pragma unroll
    for (int o = 1; o < 16; o <<= 1) ps += __shfl_xor(ps, o, 64);
    if (lane16 == 0) psum[((size_t)b*64 + blockIdx.x)*CH + c0 + cl] = ps;
    ushort4 bv; bv.x=f2b(v.x); bv.y=f2b(v.y); bv.z=f2b(v.z); bv.w=f2b(v.w);
    *(ushort4*)(xbp + (size_t)cl*NSP + nl) = bv;
    float vv[4] = {v.x, v.y, v.z, v.w};
    #pragma unroll
    for (int j = 0; j < 4; ++j) {
      int n = nl + j;
      tile[n*64 + (cl ^ (((n>>2)&7)<<2))] = vv[j];
    }
  }
  __syncthreads();
  u16* xtp = xt + ((size_t)b*NSP + n0)*CH + c0;
  #pragma unroll
  for (int q2 = 0; q2 < 4; ++q2) {
    int nl = grp + q2*16;
    int c4 = lane16*4;
    float4 v = *(const float4*)&tile[nl*64 + (c4 ^ (((nl>>2)&7)<<2))];
    ushort4 bv; bv.x=f2b(v.x); bv.y=f2b(v.y); bv.z=f2b(v.z); bv.w=f2b(v.w);
    *(ushort4*)(xtp + (size_t)nl*CH + c4) = bv;
  }
}

// ---------------- kernel 2: Gram partials, LDS-staged (m97 structure) + symmetry
__global__ __launch_bounds__(256) void k_gram(const u16* __restrict__ xb, float* __restrict__ Sp) {
  __shared__ u16 As[128*64];   // 16 KB
  __shared__ u16 Bs[128*64];   // 16 KB
  const int L = blockIdx.x;
  const int wk = (L & 7) * 48 + (L >> 3);   // bijective: 384 = 8*48, clusters 2 batches/XCD
  const int b = wk / 24;
  const int rem = wk % 24;
  const int kc = rem / 3;
  const int q = rem % 3;                    // 0:(0,0) 1:(0,1) 2:(1,1)
  const int m_base = (q == 2) ? 128 : 0;
  const int n_base = (q == 0) ? 0 : 128;
  const int t = threadIdx.x, wv = t >> 6, l = t & 63;
  const int wr = wv >> 1, wc = wv & 1;
  const int lr = l & 15, lkb = l >> 4;      // fragment row lane, k sub-block
  const int sr = l >> 3, ss = l & 7;        // staging: row-within-8, slot
  const u16* xa = xb + (size_t)b*CH*NSP;
  const int kbeg = kc * (NSP/KC);
  f32x4 acc[4][4];
  #pragma unroll
  for (int i = 0; i < 4; ++i)
    #pragma unroll
    for (int j = 0; j < 4; ++j) acc[i][j] = (f32x4){0.f,0.f,0.f,0.f};

  for (int kk = 0; kk < 8; ++kk) {
    const int kpos = kbeg + kk*64;
    #pragma unroll
    for (int j4 = 0; j4 < 4; ++j4) {
      const int j = wv*4 + j4;
      const int r = j*8 + sr;               // 0..127
      async16(&As[j*512], xa + (size_t)(m_base + r)*NSP + kpos + ((ss ^ (r & 7)) * 8));
    }
    if (q == 1) {
      #pragma unroll
      for (int j4 = 0; j4 < 4; ++j4) {
        const int j = wv*4 + j4;
        const int r = j*8 + sr;
        async16(&Bs[j*512], xa + (size_t)(n_base + r)*NSP + kpos + ((ss ^ (r & 7)) * 8));
      }
    }
    __syncthreads();
    const u16* bsrc = (q == 1) ? Bs : As;
    #pragma unroll
    for (int ks = 0; ks < 2; ++ks) {
      bf16x8 A[4], Bf[4];
      #pragma unroll
      for (int mt = 0; mt < 4; ++mt) {
        const int ra = wr*64 + mt*16 + lr;
        A[mt] = *(const bf16x8*)(As + ra*64 + (((ks*4 + lkb) ^ (ra & 7)) * 8));
      }
      #pragma unroll
      for (int nt = 0; nt < 4; ++nt) {
        const int rb = wc*64 + nt*16 + lr;
        Bf[nt] = *(const bf16x8*)(bsrc + rb*64 + (((ks*4 + lkb) ^ (rb & 7)) * 8));
      }
      #pragma unroll
      for (int mt = 0; mt < 4; ++mt)
        #pragma unroll
        for (int nt = 0; nt < 4; ++nt)
          acc[mt][nt] = __builtin_amdgcn_mfma_f32_16x16x32_bf16(A[mt], Bf[nt], acc[mt][nt], 0, 0, 0);
    }
    __syncthreads();
  }
  float* Sb = Sp + (size_t)(b*KC + kc)*CH*CH;
  const int r0 = (l >> 4) * 4;
  #pragma unroll
  for (int mt = 0; mt < 4; ++mt)
    #pragma unroll
    for (int nt = 0; nt < 4; ++nt)
      #pragma unroll
      for (int rr = 0; rr < 4; ++rr)
        Sb[(size_t)(m_base + wr*64 + mt*16 + r0 + rr)*CH + n_base + wc*64 + nt*16 + lr]
          = acc[mt][nt][rr];
}

// ---------------- reduce partials with symmetric fill
__global__ __launch_bounds__(256) void k_red(const float* __restrict__ Sp, float* __restrict__ S) {
  __shared__ float tl[64*65];
  const int b = blockIdx.y, tt = blockIdx.x, t = threadIdx.x;
  const int qq = tt >> 2, sub = tt & 3;
  const int qi = (qq == 2) ? 1 : 0, qj = (qq == 0) ? 0 : 1;
  const int row0 = qi*128 + (sub >> 1)*64, col0 = qj*128 + (sub & 1)*64;
  const float* p = Sp + (size_t)b*KC*CH*CH;
  float* Sb = S + (size_t)b*CH*CH;
  float4 sum[4];
  #pragma unroll
  for (int k = 0; k < 4; ++k) {
    const int slot = t + k*256;                 // float4 slot in 64x64 tile
    const int r = slot >> 4, c4 = (slot & 15) * 4;
    float4 s = {0.f,0.f,0.f,0.f};
    #pragma unroll
    for (int kc = 0; kc < KC; ++kc) {
      float4 v = *(const float4*)(p + (size_t)kc*CH*CH + (size_t)(row0 + r)*CH + col0 + c4);
      s.x += v.x; s.y += v.y; s.z += v.z; s.w += v.w;
    }
    sum[k] = s;
    *(float4*)(Sb + (size_t)(row0 + r)*CH + col0 + c4) = s;
  }
  if (qq == 1) {                                // mirror to (1,0)
    #pragma unroll
    for (int k = 0; k < 4; ++k) {
      const int slot = t + k*256;
      const int r = slot >> 4, c4 = (slot & 15) * 4;
      tl[r*65 + c4+0] = sum[k].x; tl[r*65 + c4+1] = sum[k].y;
      tl[r*65 + c4+2] = sum[k].z; tl[r*65 + c4+3] = sum[k].w;
    }
    __syncthreads();
    #pragma unroll
    for (int k = 0; k < 4; ++k) {
      const int slot = t + k*256;
      const int r = slot >> 4, c4 = (slot & 15) * 4;
      float4 v = { tl[(c4+0)*65 + r], tl[(c4+1)*65 + r], tl[(c4+2)*65 + r], tl[(c4+3)*65 + r] };
      *(float4*)(Sb + (size_t)(col0 + r)*CH + row0 + c4) = v;
    }
  }
}

// ---------------- k_vec2: s from psum; KS = KT^T s; Es = E s; qs = q.s  (per batch)
__global__ __launch_bounds__(256) void k_vec2(const float* __restrict__ psum,
    const float* __restrict__ E, const float* __restrict__ KT,
    const float* __restrict__ q, float* __restrict__ KS, float* __restrict__ Es,
    float* __restrict__ qs) {
  __shared__ float ls[CH];
  __shared__ float rbuf[4];
  const int b = blockIdx.x, t = threadIdx.x;
  float s = 0.f;
  for (int xb = 0; xb < 64; ++xb) s += psum[((size_t)b*64 + xb)*CH + t];
  ls[t] = s;
  __syncthreads();
  float ks = 0.f;
  for (int a = 0; a < CH; ++a) ks += KT[(size_t)a*CH + t] * ls[a];
  KS[(size_t)b*CH + t] = ks;
  float es = 0.f;
  for (int c = 0; c < CH; ++c) es += E[(size_t)t*CH + c] * ls[c];
  Es[(size_t)b*CH + t] = es;
  float p = q[t] * ls[t];
  #pragma unroll
  for (int o = 1; o < 64; o <<= 1) p += __shfl_xor(p, o, 64);
  if ((t & 63) == 0) rbuf[t >> 6] = p;
  __syncthreads();
  if (t == 0) qs[b] = rbuf[0] + rbuf[1] + rbuf[2] + rbuf[3];
}

// ---------------- k_RP: fused R = E·S (LDS-resident) then P = (inv/N)(R·KT + rank1s) + I
// grid (32, BATCH), block 256. Also computes d vector inline.
__global__ __launch_bounds__(256) void k_RP(const float* __restrict__ S,
    const float* __restrict__ E, const float* __restrict__ KT,
    const float* __restrict__ q, const float* __restrict__ KS,
    const float* __restrict__ Es, const float* __restrict__ qs,
    const float* __restrict__ wg, const float* __restrict__ tphi,
    const float* __restrict__ inv, const float* __restrict__ dconst,
    const float* __restrict__ tb, u16* __restrict__ Pb, float* __restrict__ dv) {
  __shared__ float lEt[2048];
  __shared__ float lRt[2048];
  __shared__ float red[32];
  const int b = blockIdx.y, o0 = blockIdx.x*8, t = threadIdx.x;
  #pragma unroll
  for (int k = 0; k < 8; ++k) { int idx = k*256 + t;
    lEt[idx] = E[(size_t)(o0 + (idx & 7))*CH + (idx >> 3)]; }
  __syncthreads();
  const float* Sb = S + (size_t)b*CH*CH;
  float acc[8] = {0.f};
  for (int c = 0; c < CH; ++c) {
    float sv = Sb[(size_t)c*CH + t];
    #pragma unroll
    for (int r = 0; r < 8; ++r) acc[r] += lEt[c*8 + r] * sv;
  }
  // R rows into LDS (transposed for the second GEMM) + Rq partial reduce
  #pragma unroll
  for (int r = 0; r < 8; ++r) lRt[t*8 + r] = acc[r];
  const float qt = q[t];
  #pragma unroll
  for (int r = 0; r < 8; ++r) {
    float p = acc[r] * qt;
    #pragma unroll
    for (int o = 1; o < 64; o <<= 1) p += __shfl_xor(p, o, 64);
    if ((t & 63) == 0) red[r*4 + (t >> 6)] = p;
  }
  __syncthreads();
  float acc2[8] = {0.f};
  for (int a = 0; a < CH; ++a) {
    float kv = KT[(size_t)a*CH + t];
    #pragma unroll
    for (int r = 0; r < 8; ++r) acc2[r] += lRt[a*8 + r] * kv;
  }
  const float ksv = KS[(size_t)b*CH + t], tpv = tphi[t];
  u16* Pbb = Pb + (size_t)b*CH*CH;
  #pragma unroll
  for (int r = 0; r < 8; ++r) {
    int o = o0 + r;
    float val = (acc2[r] + wg[o]*ksv + (Es[(size_t)b*CH + o] + (float)NSP*wg[o])*tpv)
                * inv[o] * (1.f/(float)NSP);
    if (o == t) val += 1.f;      // fold residual: P + I
    Pbb[(size_t)o*CH + t] = f2b(val);
  }
  if (t < 8) {
    int o = o0 + t;
    float iv = inv[o], wgo = wg[o], tb0 = tb[0];
    float rq = red[t*4] + red[t*4+1] + red[t*4+2] + red[t*4+3];
    float t2 = rq + wgo*qs[b] + Es[(size_t)b*CH + o]*tb0;
    dv[(size_t)b*CH + o] = iv*(t2*(1.f/(float)NSP) + wgo*tb0) + dconst[o];
  }
}

// ---------------- apply: out = (P+I) X + d 1^T  (LDS-staged B, 8 waves)
__global__ __launch_bounds__(512, 8) void k_apply(const u16* __restrict__ Pb,
    const u16* __restrict__ xt, const float* __restrict__ dv,
    float* __restrict__ out) {
  __shared__ u16 xs[64*256];     // 32 KB, XOR-swizzled 16B slots
  const int b = blockIdx.y, n0 = blockIdx.x*64;
  const int t = threadIdx.x, w = t >> 6, l = t & 63;
  {
    const u16* src = xt + ((size_t)b*NSP + n0)*CH;
    const int r = t >> 3, sbase = t & 7;
    #pragma unroll
    for (int it = 0; it < 4; ++it) {
      int slot = sbase + it*8;         // 0..31 (16B slots within 512B row)
      bf16x8 v = *(const bf16x8*)(src + (size_t)r*CH + slot*8);
      *(bf16x8*)(xs + r*256 + ((slot ^ (r & 7)) * 8)) = v;
    }
  }
  __syncthreads();
  const int m0 = w*32;
  const int lr = l & 15, lkb = l >> 4;   // k sub-block 0..3 (8 elems each)
  const int sw = lr & 7;
  const u16* Pp = Pb + (size_t)b*CH*CH;
  f32x4 acc[2][4];
  #pragma unroll
  for (int i = 0; i < 2; ++i)
    #pragma unroll
    for (int j = 0; j < 4; ++j) acc[i][j] = (f32x4){0.f,0.f,0.f,0.f};
  #pragma unroll
  for (int kk = 0; kk < 8; ++kk) {
    bf16x8 A[2], Bf[4];
    #pragma unroll
    for (int mt = 0; mt < 2; ++mt)
      A[mt] = *(const bf16x8*)(Pp + (size_t)(m0 + mt*16 + lr)*CH + kk*32 + lkb*8);
    #pragma unroll
    for (int nt = 0; nt < 4; ++nt) {
      int slot = kk*4 + lkb;
      Bf[nt] = *(const bf16x8*)(xs + (nt*16 + lr)*256 + ((slot ^ sw) * 8));
    }
    #pragma unroll
    for (int mt = 0; mt < 2; ++mt)
      #pragma unroll
      for (int nt = 0; nt < 4; ++nt)
        acc[mt][nt] = __builtin_amdgcn_mfma_f32_16x16x32_bf16(A[mt], Bf[nt], acc[mt][nt], 0, 0, 0);
  }
  float* ob = out + (size_t)b*CH*NSP;
  const int r0 = (l >> 4) * 4;
  #pragma unroll
  for (int mt = 0; mt < 2; ++mt)
    #pragma unroll
    for (int rr = 0; rr < 4; ++rr) {
      int row = m0 + mt*16 + r0 + rr;
      float dval = dv[(size_t)b*CH + row];
      #pragma unroll
      for (int nt = 0; nt < 4; ++nt) {
        int col = n0 + nt*16 + lr;
        ob[(size_t)row*NSP + col] = acc[mt][nt][rr] + dval;
      }
    }
}

// ---------------- workspace layout (bytes)
static constexpr size_t XT_OFF = 0;              // bf16 [16][4096][256]  33,554,432
static constexpr size_t S_OFF  = 33554432;       // f32  [16][256][256]    4,194,304
static constexpr size_t PB_OFF = 37748736;       // bf16 [16][256][256]    2,097,152
static constexpr size_t PS_OFF = 39845888;       // f32  [16][64][256]     1,048,576
static constexpr size_t E_OFF  = 40894464;       // f32  [256][256]          262,144
static constexpr size_t KT_OFF = 41156608;       // f32  [256][256]          262,144
static constexpr size_t WG_OFF = 41418752;       // f32 [256] (1K pad each follows)
static constexpr size_t TP_OFF = 41419776;
static constexpr size_t QV_OFF = 41420800;
static constexpr size_t IV_OFF = 41421824;
static constexpr size_t DC_OFF = 41422848;
static constexpr size_t TB_OFF = 41423872;
static constexpr size_t KS_OFF = 41424896;       // f32 [16][256] 16,384
static constexpr size_t ES_OFF = 41441280;       // f32 [16][256] 16,384
static constexpr size_t QS_OFF = 41457664;       // f32 [16] (1K pad)
static constexpr size_t DV_OFF = 41458688;       // f32 [16][256] 16,384

extern "C" void kernel_launch(void* const* d_in, const int* in_sizes, int n_in,
                              void* d_out, int out_size, void* d_ws, size_t ws_size,
                              hipStream_t stream) {
  const float* x       = (const float*)d_in[0];
  const float* g_w     = (const float*)d_in[1];
  const float* g_b     = (const float*)d_in[2];
  const float* theta_w = (const float*)d_in[3];
  const float* theta_b = (const float*)d_in[4];
  const float* phi_w   = (const float*)d_in[5];
  const float* phi_b   = (const float*)d_in[6];
  const float* w_w     = (const float*)d_in[7];
  const float* w_b     = (const float*)d_in[8];
  const float* bn_g    = (const float*)d_in[9];
  const float* bn_b    = (const float*)d_in[10];
  const float* bn_m    = (const float*)d_in[11];
  const float* bn_v    = (const float*)d_in[12];
  float* out = (float*)d_out;
  char* ws = (char*)d_ws;
  u16*   XT = (u16*)(ws + XT_OFF);
  float* S  = (float*)(ws + S_OFF);
  u16*   Pb = (u16*)(ws + PB_OFF);
  float* PS = (float*)(ws + PS_OFF);
  float* E  = (float*)(ws + E_OFF);
  float* KT = (float*)(ws + KT_OFF);
  float* WG = (float*)(ws + WG_OFF);
  float* TP = (float*)(ws + TP_OFF);
  float* QV = (float*)(ws + QV_OFF);
  float* IV = (float*)(ws + IV_OFF);
  float* DC = (float*)(ws + DC_OFF);
  float* TB = (float*)(ws + TB_OFF);
  float* KS = (float*)(ws + KS_OFF);
  float* ES = (float*)(ws + ES_OFF);
  float* QS = (float*)(ws + QS_OFF);
  float* DV = (float*)(ws + DV_OFF);
  // d_out scratch: Xb bf16 [0, 33.5MB); Sp partials [33.5MB, 67MB). Dead before k_apply.
  u16*   Xb = (u16*)d_out;
  float* Sp = (float*)((char*)d_out + 33554432);

  k_const<<<dim3(65),                    256, 0, stream>>>(w_w, g_w, g_b, theta_w, theta_b,
                                                           phi_w, phi_b, w_b, bn_g, bn_b, bn_m, bn_v,
                                                           E, KT, WG, TP, QV, IV, DC, TB);
  k_prep <<<dim3(NSP/64, CH/64, BATCH),  256, 0, stream>>>(x, Xb, XT, PS);
  k_gram <<<dim3(384),                   256, 0, stream>>>(Xb, Sp);
  k_red  <<<dim3(12, BATCH),             256, 0, stream>>>(Sp, S);
  k_vec2 <<<dim3(BATCH),                 256, 0, stream>>>(PS, E, KT, QV, KS, ES, QS);
  k_RP   <<<dim3(32, BATCH),             256, 0, stream>>>(S, E, KT, QV, KS, ES, QS, WG, TP, IV, DC, TB, Pb, DV);
  k_apply<<<dim3(NSP/64, BATCH),         512, 0, stream>>>(Pb, XT, DV, out);
}

// Round 6
// 131.226 us; speedup vs baseline: 2.6002x; 1.0394x over previous
//
#include <hip/hip_runtime.h>
#include <stdint.h>

#define BATCH 16
#define CH    256
#define CI    128
#define NSP   4096
#define KC    8          // K-split chunks for the Gram GEMM
#define EPSV  1e-5f

typedef unsigned short u16;
typedef __attribute__((ext_vector_type(4))) float f32x4;
typedef __attribute__((ext_vector_type(8))) short bf16x8;

__device__ __forceinline__ u16 f2b(float f) {
  uint32_t u = __float_as_uint(f);
  uint32_t r = u + 0x7FFFu + ((u >> 16) & 1u);   // round-to-nearest-even
  return (u16)(r >> 16);
}

__device__ __forceinline__ void async16(void* lds, const void* g) {
  __builtin_amdgcn_global_load_lds(
      (const __attribute__((address_space(1))) unsigned int*)g,
      (__attribute__((address_space(3))) unsigned int*)lds, 16, 0, 0);
}

// ---------------- k_const: batch-independent matrices/vectors
__global__ __launch_bounds__(256) void k_const(const float* __restrict__ w_w,
    const float* __restrict__ g_w, const float* __restrict__ g_b,
    const float* __restrict__ theta_w, const float* __restrict__ theta_b,
    const float* __restrict__ phi_w, const float* __restrict__ phi_b,
    const float* __restrict__ w_b, const float* __restrict__ bn_g,
    const float* __restrict__ bn_b, const float* __restrict__ bn_m,
    const float* __restrict__ bn_v,
    float* __restrict__ E, float* __restrict__ KT, float* __restrict__ wg,
    float* __restrict__ tphi, float* __restrict__ q, float* __restrict__ inv,
    float* __restrict__ dconst, float* __restrict__ tb) {
  __shared__ float lbuf[1024];
  const int blk = blockIdx.x, t = threadIdx.x;
  if (blk < 32) {                 // E rows o0..o0+7
    const int o0 = blk*8;
    #pragma unroll
    for (int k = 0; k < 4; ++k) { int idx = k*256 + t;
      lbuf[idx] = w_w[(size_t)(o0 + (idx & 7))*CI + (idx >> 3)]; }
    __syncthreads();
    float acc[8] = {0.f};
    for (int j = 0; j < CI; ++j) {
      float gv = g_w[(size_t)j*CH + t];
      #pragma unroll
      for (int r = 0; r < 8; ++r) acc[r] += lbuf[j*8 + r] * gv;
    }
    #pragma unroll
    for (int r = 0; r < 8; ++r) E[(size_t)(o0 + r)*CH + t] = acc[r];
  } else if (blk < 64) {          // KT rows a0..a0+7
    const int a0 = (blk - 32)*8;
    #pragma unroll
    for (int k = 0; k < 4; ++k) { int idx = k*256 + t;
      lbuf[idx] = phi_w[(size_t)(idx >> 3)*CH + a0 + (idx & 7)]; }
    __syncthreads();
    float acc[8] = {0.f};
    for (int i = 0; i < CI; ++i) {
      float tv = theta_w[(size_t)i*CH + t];
      #pragma unroll
      for (int u = 0; u < 8; ++u) acc[u] += lbuf[i*8 + u] * tv;
    }
    #pragma unroll
    for (int u = 0; u < 8; ++u) KT[(size_t)(a0 + u)*CH + t] = acc[u];
  } else {                        // vectors
    float iv = bn_g[t] * rsqrtf(bn_v[t] + EPSV);
    inv[t] = iv;
    dconst[t] = iv*w_b[t] + bn_b[t] - bn_m[t]*iv;
    float a = 0.f;
    for (int j = 0; j < CI; ++j) a += w_w[(size_t)t*CI + j] * g_b[j];
    wg[t] = a;
    float tp = 0.f, qq = 0.f;
    for (int i = 0; i < CI; ++i) {
      tp += theta_w[(size_t)i*CH + t] * phi_b[i];
      qq += phi_w[(size_t)i*CH + t] * theta_b[i];
    }
    tphi[t] = tp; q[t] = qq;
    lbuf[t] = (t < CI) ? theta_b[t]*phi_b[t] : 0.f;
    __syncthreads();
    for (int s2 = 128; s2 > 0; s2 >>= 1) { if (t < s2) lbuf[t] += lbuf[t + s2]; __syncthreads(); }
    if (t == 0) tb[0] = lbuf[0];
  }
}

// ---------------- kernel 1: bf16 convert (row-major + transposed) + row-sum partials
__global__ __launch_bounds__(256) void k_prep(const float* __restrict__ x,
    u16* __restrict__ xb, u16* __restrict__ xt, float* __restrict__ psum) {
  __shared__ float tile[64*64];
  const int b = blockIdx.z, c0 = blockIdx.y*64, n0 = blockIdx.x*64;
  const int t = threadIdx.x;
  const int lane16 = t & 15;
  const int grp = t >> 4;              // 0..15
  const float* xp = x + ((size_t)b*CH + c0)*NSP + n0;
  u16* xbp = xb + ((size_t)b*CH + c0)*NSP + n0;
  #pragma unroll
  for (int p = 0; p < 4; ++p) {
    int cl = grp + p*16;               // row within tile, 0..63
    int nl = lane16*4;
    float4 v = *(const float4*)(xp + (size_t)cl*NSP + nl);
    float ps = v.x + v.y + v.z + v.w;
    #pragma unroll
    for (int o = 1; o < 16; o <<= 1) ps += __shfl_xor(ps, o, 64);
    if (lane16 == 0) psum[((size_t)b*64 + blockIdx.x)*CH + c0 + cl] = ps;
    ushort4 bv; bv.x=f2b(v.x); bv.y=f2b(v.y); bv.z=f2b(v.z); bv.w=f2b(v.w);
    *(ushort4*)(xbp + (size_t)cl*NSP + nl) = bv;
    float vv[4] = {v.x, v.y, v.z, v.w};
    #pragma unroll
    for (int j = 0; j < 4; ++j) {
      int n = nl + j;
      tile[n*64 + (cl ^ (((n>>2)&7)<<2))] = vv[j];
    }
  }
  __syncthreads();
  u16* xtp = xt + ((size_t)b*NSP + n0)*CH + c0;
  #pragma unroll
  for (int q2 = 0; q2 < 4; ++q2) {
    int nl = grp + q2*16;
    int c4 = lane16*4;
    float4 v = *(const float4*)&tile[nl*64 + (c4 ^ (((nl>>2)&7)<<2))];
    ushort4 bv; bv.x=f2b(v.x); bv.y=f2b(v.y); bv.z=f2b(v.z); bv.w=f2b(v.w);
    *(ushort4*)(xtp + (size_t)nl*CH + c4) = bv;
  }
}

// ---------------- kernel 2: Gram partials, LDS-staged (m97 structure) + symmetry
__global__ __launch_bounds__(256) void k_gram(const u16* __restrict__ xb, float* __restrict__ Sp) {
  __shared__ u16 As[128*64];   // 16 KB
  __shared__ u16 Bs[128*64];   // 16 KB
  const int L = blockIdx.x;
  const int wk = (L & 7) * 48 + (L >> 3);   // bijective: 384 = 8*48, clusters 2 batches/XCD
  const int b = wk / 24;
  const int rem = wk % 24;
  const int kc = rem / 3;
  const int q = rem % 3;                    // 0:(0,0) 1:(0,1) 2:(1,1)
  const int m_base = (q == 2) ? 128 : 0;
  const int n_base = (q == 0) ? 0 : 128;
  const int t = threadIdx.x, wv = t >> 6, l = t & 63;
  const int wr = wv >> 1, wc = wv & 1;
  const int lr = l & 15, lkb = l >> 4;      // fragment row lane, k sub-block
  const int sr = l >> 3, ss = l & 7;        // staging: row-within-8, slot
  const u16* xa = xb + (size_t)b*CH*NSP;
  const int kbeg = kc * (NSP/KC);
  f32x4 acc[4][4];
  #pragma unroll
  for (int i = 0; i < 4; ++i)
    #pragma unroll
    for (int j = 0; j < 4; ++j) acc[i][j] = (f32x4){0.f,0.f,0.f,0.f};

  for (int kk = 0; kk < 8; ++kk) {
    const int kpos = kbeg + kk*64;
    #pragma unroll
    for (int j4 = 0; j4 < 4; ++j4) {
      const int j = wv*4 + j4;
      const int r = j*8 + sr;               // 0..127
      async16(&As[j*512], xa + (size_t)(m_base + r)*NSP + kpos + ((ss ^ (r & 7)) * 8));
    }
    if (q == 1) {
      #pragma unroll
      for (int j4 = 0; j4 < 4; ++j4) {
        const int j = wv*4 + j4;
        const int r = j*8 + sr;
        async16(&Bs[j*512], xa + (size_t)(n_base + r)*NSP + kpos + ((ss ^ (r & 7)) * 8));
      }
    }
    __syncthreads();
    const u16* bsrc = (q == 1) ? Bs : As;
    #pragma unroll
    for (int ks = 0; ks < 2; ++ks) {
      bf16x8 A[4], Bf[4];
      #pragma unroll
      for (int mt = 0; mt < 4; ++mt) {
        const int ra = wr*64 + mt*16 + lr;
        A[mt] = *(const bf16x8*)(As + ra*64 + (((ks*4 + lkb) ^ (ra & 7)) * 8));
      }
      #pragma unroll
      for (int nt = 0; nt < 4; ++nt) {
        const int rb = wc*64 + nt*16 + lr;
        Bf[nt] = *(const bf16x8*)(bsrc + rb*64 + (((ks*4 + lkb) ^ (rb & 7)) * 8));
      }
      #pragma unroll
      for (int mt = 0; mt < 4; ++mt)
        #pragma unroll
        for (int nt = 0; nt < 4; ++nt)
          acc[mt][nt] = __builtin_amdgcn_mfma_f32_16x16x32_bf16(A[mt], Bf[nt], acc[mt][nt], 0, 0, 0);
    }
    __syncthreads();
  }
  float* Sb = Sp + (size_t)(b*KC + kc)*CH*CH;
  const int r0 = (l >> 4) * 4;
  #pragma unroll
  for (int mt = 0; mt < 4; ++mt)
    #pragma unroll
    for (int nt = 0; nt < 4; ++nt)
      #pragma unroll
      for (int rr = 0; rr < 4; ++rr)
        Sb[(size_t)(m_base + wr*64 + mt*16 + r0 + rr)*CH + n_base + wc*64 + nt*16 + lr]
          = acc[mt][nt][rr];
}

// ---------------- reduce partials with symmetric fill
__global__ __launch_bounds__(256) void k_red(const float* __restrict__ Sp, float* __restrict__ S) {
  __shared__ float tl[64*65];
  const int b = blockIdx.y, tt = blockIdx.x, t = threadIdx.x;
  const int qq = tt >> 2, sub = tt & 3;
  const int qi = (qq == 2) ? 1 : 0, qj = (qq == 0) ? 0 : 1;
  const int row0 = qi*128 + (sub >> 1)*64, col0 = qj*128 + (sub & 1)*64;
  const float* p = Sp + (size_t)b*KC*CH*CH;
  float* Sb = S + (size_t)b*CH*CH;
  float4 sum[4];
  #pragma unroll
  for (int k = 0; k < 4; ++k) {
    const int slot = t + k*256;                 // float4 slot in 64x64 tile
    const int r = slot >> 4, c4 = (slot & 15) * 4;
    float4 s = {0.f,0.f,0.f,0.f};
    #pragma unroll
    for (int kc = 0; kc < KC; ++kc) {
      float4 v = *(const float4*)(p + (size_t)kc*CH*CH + (size_t)(row0 + r)*CH + col0 + c4);
      s.x += v.x; s.y += v.y; s.z += v.z; s.w += v.w;
    }
    sum[k] = s;
    *(float4*)(Sb + (size_t)(row0 + r)*CH + col0 + c4) = s;
  }
  if (qq == 1) {                                // mirror to (1,0)
    #pragma unroll
    for (int k = 0; k < 4; ++k) {
      const int slot = t + k*256;
      const int r = slot >> 4, c4 = (slot & 15) * 4;
      tl[r*65 + c4+0] = sum[k].x; tl[r*65 + c4+1] = sum[k].y;
      tl[r*65 + c4+2] = sum[k].z; tl[r*65 + c4+3] = sum[k].w;
    }
    __syncthreads();
    #pragma unroll
    for (int k = 0; k < 4; ++k) {
      const int slot = t + k*256;
      const int r = slot >> 4, c4 = (slot & 15) * 4;
      float4 v = { tl[(c4+0)*65 + r], tl[(c4+1)*65 + r], tl[(c4+2)*65 + r], tl[(c4+3)*65 + r] };
      *(float4*)(Sb + (size_t)(col0 + r)*CH + row0 + c4) = v;
    }
  }
}

// ---------------- k_vec2: s from psum; KS = KT^T s; Es = E s; qs = q.s  (per batch)
__global__ __launch_bounds__(256) void k_vec2(const float* __restrict__ psum,
    const float* __restrict__ E, const float* __restrict__ KT,
    const float* __restrict__ q, float* __restrict__ KS, float* __restrict__ Es,
    float* __restrict__ qs) {
  __shared__ float ls[CH];
  __shared__ float rbuf[4];
  const int b = blockIdx.x, t = threadIdx.x;
  float s = 0.f;
  for (int xb = 0; xb < 64; ++xb) s += psum[((size_t)b*64 + xb)*CH + t];
  ls[t] = s;
  __syncthreads();
  float ks = 0.f;
  for (int a = 0; a < CH; ++a) ks += KT[(size_t)a*CH + t] * ls[a];
  KS[(size_t)b*CH + t] = ks;
  float es = 0.f;
  for (int c = 0; c < CH; ++c) es += E[(size_t)t*CH + c] * ls[c];
  Es[(size_t)b*CH + t] = es;
  float p = q[t] * ls[t];
  #pragma unroll
  for (int o = 1; o < 64; o <<= 1) p += __shfl_xor(p, o, 64);
  if ((t & 63) == 0) rbuf[t >> 6] = p;
  __syncthreads();
  if (t == 0) qs[b] = rbuf[0] + rbuf[1] + rbuf[2] + rbuf[3];
}

// ---------------- k_RP: fused R = E·S (LDS-resident) then P = (inv/N)(R·KT + rank1s) + I
__global__ __launch_bounds__(256) void k_RP(const float* __restrict__ S,
    const float* __restrict__ E, const float* __restrict__ KT,
    const float* __restrict__ q, const float* __restrict__ KS,
    const float* __restrict__ Es, const float* __restrict__ qs,
    const float* __restrict__ wg, const float* __restrict__ tphi,
    const float* __restrict__ inv, const float* __restrict__ dconst,
    const float* __restrict__ tb, u16* __restrict__ Pb, float* __restrict__ dv) {
  __shared__ float lEt[2048];
  __shared__ float lRt[2048];
  __shared__ float red[32];
  const int b = blockIdx.y, o0 = blockIdx.x*8, t = threadIdx.x;
  #pragma unroll
  for (int k = 0; k < 8; ++k) { int idx = k*256 + t;
    lEt[idx] = E[(size_t)(o0 + (idx & 7))*CH + (idx >> 3)]; }
  __syncthreads();
  const float* Sb = S + (size_t)b*CH*CH;
  float acc[8] = {0.f};
  for (int c = 0; c < CH; ++c) {
    float sv = Sb[(size_t)c*CH + t];
    #pragma unroll
    for (int r = 0; r < 8; ++r) acc[r] += lEt[c*8 + r] * sv;
  }
  #pragma unroll
  for (int r = 0; r < 8; ++r) lRt[t*8 + r] = acc[r];
  const float qt = q[t];
  #pragma unroll
  for (int r = 0; r < 8; ++r) {
    float p = acc[r] * qt;
    #pragma unroll
    for (int o = 1; o < 64; o <<= 1) p += __shfl_xor(p, o, 64);
    if ((t & 63) == 0) red[r*4 + (t >> 6)] = p;
  }
  __syncthreads();
  float acc2[8] = {0.f};
  for (int a = 0; a < CH; ++a) {
    float kv = KT[(size_t)a*CH + t];
    #pragma unroll
    for (int r = 0; r < 8; ++r) acc2[r] += lRt[a*8 + r] * kv;
  }
  const float ksv = KS[(size_t)b*CH + t], tpv = tphi[t];
  u16* Pbb = Pb + (size_t)b*CH*CH;
  #pragma unroll
  for (int r = 0; r < 8; ++r) {
    int o = o0 + r;
    float val = (acc2[r] + wg[o]*ksv + (Es[(size_t)b*CH + o] + (float)NSP*wg[o])*tpv)
                * inv[o] * (1.f/(float)NSP);
    if (o == t) val += 1.f;      // fold residual: P + I
    Pbb[(size_t)o*CH + t] = f2b(val);
  }
  if (t < 8) {
    int o = o0 + t;
    float iv = inv[o], wgo = wg[o], tb0 = tb[0];
    float rq = red[t*4] + red[t*4+1] + red[t*4+2] + red[t*4+3];
    float t2 = rq + wgo*qs[b] + Es[(size_t)b*CH + o]*tb0;
    dv[(size_t)b*CH + o] = iv*(t2*(1.f/(float)NSP) + wgo*tb0) + dconst[o];
  }
}

// ---------------- apply: out = (P+I) X + d 1^T  (LDS-staged B, coalesced f32 epilogue)
// grid (NSP/64, BATCH), block 512 = 8 waves, wave tile 32 rows x 64 cols
__global__ __launch_bounds__(512, 4) void k_apply(const u16* __restrict__ Pb,
    const u16* __restrict__ xt, const float* __restrict__ dv,
    float* __restrict__ out) {
  __shared__ union {
    u16   bx[64*256];        // 32 KB bf16 B-tile (XOR-swizzled 16B slots)
    float fe[8][16][68];     // 34 KB per-wave f32 epilogue buffers (stride 68)
  } sm;
  const int b = blockIdx.y, n0 = blockIdx.x*64;
  const int t = threadIdx.x, w = t >> 6, l = t & 63;
  {
    const u16* src = xt + ((size_t)b*NSP + n0)*CH;
    const int r = t >> 3, sbase = t & 7;
    #pragma unroll
    for (int it = 0; it < 4; ++it) {
      int slot = sbase + it*8;         // 0..31 (16B slots within 512B row)
      bf16x8 v = *(const bf16x8*)(src + (size_t)r*CH + slot*8);
      *(bf16x8*)(sm.bx + r*256 + ((slot ^ (r & 7)) * 8)) = v;
    }
  }
  __syncthreads();
  const int m0 = w*32;
  const int lr = l & 15, lkb = l >> 4;   // k sub-block 0..3 (8 elems each)
  const int sw = lr & 7;
  const u16* Pp = Pb + (size_t)b*CH*CH;
  f32x4 acc[2][4];
  #pragma unroll
  for (int i = 0; i < 2; ++i)
    #pragma unroll
    for (int j = 0; j < 4; ++j) acc[i][j] = (f32x4){0.f,0.f,0.f,0.f};
  #pragma unroll
  for (int kk = 0; kk < 8; ++kk) {
    bf16x8 A[2], Bf[4];
    #pragma unroll
    for (int mt = 0; mt < 2; ++mt)
      A[mt] = *(const bf16x8*)(Pp + (size_t)(m0 + mt*16 + lr)*CH + kk*32 + lkb*8);
    #pragma unroll
    for (int nt = 0; nt < 4; ++nt) {
      int slot = kk*4 + lkb;
      Bf[nt] = *(const bf16x8*)(sm.bx + (nt*16 + lr)*256 + ((slot ^ sw) * 8));
    }
    #pragma unroll
    for (int mt = 0; mt < 2; ++mt)
      #pragma unroll
      for (int nt = 0; nt < 4; ++nt)
        acc[mt][nt] = __builtin_amdgcn_mfma_f32_16x16x32_bf16(A[mt], Bf[nt], acc[mt][nt], 0, 0, 0);
  }
  __syncthreads();                     // B-tile dead; reuse LDS for epilogue
  float* ob = out + (size_t)b*CH*NSP;
  const int r0 = (l >> 4) * 4;
  #pragma unroll
  for (int mt = 0; mt < 2; ++mt) {
    // scatter wave tile (16 rows x 64 cols) into wave-private LDS, +d folded
    #pragma unroll
    for (int rr = 0; rr < 4; ++rr) {
      float dval = dv[(size_t)b*CH + m0 + mt*16 + r0 + rr];
      #pragma unroll
      for (int nt = 0; nt < 4; ++nt)
        sm.fe[w][r0 + rr][nt*16 + lr] = acc[mt][nt][rr] + dval;
    }
    // gather coalesced: lanes 0-15 cover 256B contiguous per row, float4 stores
    #pragma unroll
    for (int i = 0; i < 4; ++i) {
      int s = l + 64*i;
      int rrow = s >> 4, c4 = (s & 15) * 4;
      float4 v = *(const float4*)&sm.fe[w][rrow][c4];
      *(float4*)&ob[(size_t)(m0 + mt*16 + rrow)*NSP + n0 + c4] = v;
    }
  }
}

// ---------------- workspace layout (bytes)
static constexpr size_t XT_OFF = 0;              // bf16 [16][4096][256]  33,554,432
static constexpr size_t S_OFF  = 33554432;       // f32  [16][256][256]    4,194,304
static constexpr size_t PB_OFF = 37748736;       // bf16 [16][256][256]    2,097,152
static constexpr size_t PS_OFF = 39845888;       // f32  [16][64][256]     1,048,576
static constexpr size_t E_OFF  = 40894464;       // f32  [256][256]          262,144
static constexpr size_t KT_OFF = 41156608;       // f32  [256][256]          262,144
static constexpr size_t WG_OFF = 41418752;       // f32 [256] (1K pad each follows)
static constexpr size_t TP_OFF = 41419776;
static constexpr size_t QV_OFF = 41420800;
static constexpr size_t IV_OFF = 41421824;
static constexpr size_t DC_OFF = 41422848;
static constexpr size_t TB_OFF = 41423872;
static constexpr size_t KS_OFF = 41424896;       // f32 [16][256] 16,384
static constexpr size_t ES_OFF = 41441280;       // f32 [16][256] 16,384
static constexpr size_t QS_OFF = 41457664;       // f32 [16] (1K pad)
static constexpr size_t DV_OFF = 41458688;       // f32 [16][256] 16,384

extern "C" void kernel_launch(void* const* d_in, const int* in_sizes, int n_in,
                              void* d_out, int out_size, void* d_ws, size_t ws_size,
                              hipStream_t stream) {
  const float* x       = (const float*)d_in[0];
  const float* g_w     = (const float*)d_in[1];
  const float* g_b     = (const float*)d_in[2];
  const float* theta_w = (const float*)d_in[3];
  const float* theta_b = (const float*)d_in[4];
  const float* phi_w   = (const float*)d_in[5];
  const float* phi_b   = (const float*)d_in[6];
  const float* w_w     = (const float*)d_in[7];
  const float* w_b     = (const float*)d_in[8];
  const float* bn_g    = (const float*)d_in[9];
  const float* bn_b    = (const float*)d_in[10];
  const float* bn_m    = (const float*)d_in[11];
  const float* bn_v    = (const float*)d_in[12];
  float* out = (float*)d_out;
  char* ws = (char*)d_ws;
  u16*   XT = (u16*)(ws + XT_OFF);
  float* S  = (float*)(ws + S_OFF);
  u16*   Pb = (u16*)(ws + PB_OFF);
  float* PS = (float*)(ws + PS_OFF);
  float* E  = (float*)(ws + E_OFF);
  float* KT = (float*)(ws + KT_OFF);
  float* WG = (float*)(ws + WG_OFF);
  float* TP = (float*)(ws + TP_OFF);
  float* QV = (float*)(ws + QV_OFF);
  float* IV = (float*)(ws + IV_OFF);
  float* DC = (float*)(ws + DC_OFF);
  float* TB = (float*)(ws + TB_OFF);
  float* KS = (float*)(ws + KS_OFF);
  float* ES = (float*)(ws + ES_OFF);
  float* QS = (float*)(ws + QS_OFF);
  float* DV = (float*)(ws + DV_OFF);
  // d_out scratch: Xb bf16 [0, 33.5MB); Sp partials [33.5MB, 67MB). Dead before k_apply.
  u16*   Xb = (u16*)d_out;
  float* Sp = (float*)((char*)d_out + 33554432);

  k_const<<<dim3(65),                    256, 0, stream>>>(w_w, g_w, g_b, theta_w, theta_b,
                                                           phi_w, phi_b, w_b, bn_g, bn_b, bn_m, bn_v,
                                                           E, KT, WG, TP, QV, IV, DC, TB);
  k_prep <<<dim3(NSP/64, CH/64, BATCH),  256, 0, stream>>>(x, Xb, XT, PS);
  k_gram <<<dim3(384),                   256, 0, stream>>>(Xb, Sp);
  k_red  <<<dim3(12, BATCH),             256, 0, stream>>>(Sp, S);
  k_vec2 <<<dim3(BATCH),                 256, 0, stream>>>(PS, E, KT, QV, KS, ES, QS);
  k_RP   <<<dim3(32, BATCH),             256, 0, stream>>>(S, E, KT, QV, KS, ES, QS, WG, TP, IV, DC, TB, Pb, DV);
  k_apply<<<dim3(NSP/64, BATCH),         512, 0, stream>>>(Pb, XT, DV, out);
}

// Round 7
// 127.328 us; speedup vs baseline: 2.6798x; 1.0306x over previous
//
#include <hip/hip_runtime.h>
#include <stdint.h>

#define BATCH 16
#define CH    256
#define CI    128
#define NSP   4096
#define KC    4          // K-split chunks for the Gram GEMM
#define EPSV  1e-5f

typedef unsigned short u16;
typedef __attribute__((ext_vector_type(4))) float f32x4;
typedef __attribute__((ext_vector_type(8))) short bf16x8;

__device__ __forceinline__ u16 f2b(float f) {
  uint32_t u = __float_as_uint(f);
  uint32_t r = u + 0x7FFFu + ((u >> 16) & 1u);   // round-to-nearest-even
  return (u16)(r >> 16);
}

__device__ __forceinline__ void async16(void* lds, const void* g) {
  __builtin_amdgcn_global_load_lds(
      (const __attribute__((address_space(1))) unsigned int*)g,
      (__attribute__((address_space(3))) unsigned int*)lds, 16, 0, 0);
}

// ---------------- k_const: batch-independent matrices/vectors
__global__ __launch_bounds__(256) void k_const(const float* __restrict__ w_w,
    const float* __restrict__ g_w, const float* __restrict__ g_b,
    const float* __restrict__ theta_w, const float* __restrict__ theta_b,
    const float* __restrict__ phi_w, const float* __restrict__ phi_b,
    const float* __restrict__ w_b, const float* __restrict__ bn_g,
    const float* __restrict__ bn_b, const float* __restrict__ bn_m,
    const float* __restrict__ bn_v,
    float* __restrict__ E, float* __restrict__ KT, float* __restrict__ wg,
    float* __restrict__ tphi, float* __restrict__ q, float* __restrict__ inv,
    float* __restrict__ dconst, float* __restrict__ tb) {
  __shared__ float lbuf[1024];
  const int blk = blockIdx.x, t = threadIdx.x;
  if (blk < 32) {                 // E rows o0..o0+7
    const int o0 = blk*8;
    #pragma unroll
    for (int k = 0; k < 4; ++k) { int idx = k*256 + t;
      lbuf[idx] = w_w[(size_t)(o0 + (idx & 7))*CI + (idx >> 3)]; }
    __syncthreads();
    float acc[8] = {0.f};
    for (int j = 0; j < CI; ++j) {
      float gv = g_w[(size_t)j*CH + t];
      #pragma unroll
      for (int r = 0; r < 8; ++r) acc[r] += lbuf[j*8 + r] * gv;
    }
    #pragma unroll
    for (int r = 0; r < 8; ++r) E[(size_t)(o0 + r)*CH + t] = acc[r];
  } else if (blk < 64) {          // KT rows a0..a0+7
    const int a0 = (blk - 32)*8;
    #pragma unroll
    for (int k = 0; k < 4; ++k) { int idx = k*256 + t;
      lbuf[idx] = phi_w[(size_t)(idx >> 3)*CH + a0 + (idx & 7)]; }
    __syncthreads();
    float acc[8] = {0.f};
    for (int i = 0; i < CI; ++i) {
      float tv = theta_w[(size_t)i*CH + t];
      #pragma unroll
      for (int u = 0; u < 8; ++u) acc[u] += lbuf[i*8 + u] * tv;
    }
    #pragma unroll
    for (int u = 0; u < 8; ++u) KT[(size_t)(a0 + u)*CH + t] = acc[u];
  } else {                        // vectors
    float iv = bn_g[t] * rsqrtf(bn_v[t] + EPSV);
    inv[t] = iv;
    dconst[t] = iv*w_b[t] + bn_b[t] - bn_m[t]*iv;
    float a = 0.f;
    for (int j = 0; j < CI; ++j) a += w_w[(size_t)t*CI + j] * g_b[j];
    wg[t] = a;
    float tp = 0.f, qq = 0.f;
    for (int i = 0; i < CI; ++i) {
      tp += theta_w[(size_t)i*CH + t] * phi_b[i];
      qq += phi_w[(size_t)i*CH + t] * theta_b[i];
    }
    tphi[t] = tp; q[t] = qq;
    lbuf[t] = (t < CI) ? theta_b[t]*phi_b[t] : 0.f;
    __syncthreads();
    for (int s2 = 128; s2 > 0; s2 >>= 1) { if (t < s2) lbuf[t] += lbuf[t + s2]; __syncthreads(); }
    if (t == 0) tb[0] = lbuf[0];
  }
}

// ---------------- kernel 1: bf16 convert (row-major + transposed) + row-sum partials
__global__ __launch_bounds__(256) void k_prep(const float* __restrict__ x,
    u16* __restrict__ xb, u16* __restrict__ xt, float* __restrict__ psum) {
  __shared__ float tile[64*64];
  const int b = blockIdx.z, c0 = blockIdx.y*64, n0 = blockIdx.x*64;
  const int t = threadIdx.x;
  const int lane16 = t & 15;
  const int grp = t >> 4;              // 0..15
  const float* xp = x + ((size_t)b*CH + c0)*NSP + n0;
  u16* xbp = xb + ((size_t)b*CH + c0)*NSP + n0;
  #pragma unroll
  for (int p = 0; p < 4; ++p) {
    int cl = grp + p*16;               // row within tile, 0..63
    int nl = lane16*4;
    float4 v = *(const float4*)(xp + (size_t)cl*NSP + nl);
    float ps = v.x + v.y + v.z + v.w;
    #pragma unroll
    for (int o = 1; o < 16; o <<= 1) ps += __shfl_xor(ps, o, 64);
    if (lane16 == 0) psum[((size_t)b*64 + blockIdx.x)*CH + c0 + cl] = ps;
    ushort4 bv; bv.x=f2b(v.x); bv.y=f2b(v.y); bv.z=f2b(v.z); bv.w=f2b(v.w);
    *(ushort4*)(xbp + (size_t)cl*NSP + nl) = bv;
    float vv[4] = {v.x, v.y, v.z, v.w};
    #pragma unroll
    for (int j = 0; j < 4; ++j) {
      int n = nl + j;
      tile[n*64 + (cl ^ (((n>>2)&7)<<2))] = vv[j];
    }
  }
  __syncthreads();
  u16* xtp = xt + ((size_t)b*NSP + n0)*CH + c0;
  #pragma unroll
  for (int q2 = 0; q2 < 4; ++q2) {
    int nl = grp + q2*16;
    int c4 = lane16*4;
    float4 v = *(const float4*)&tile[nl*64 + (c4 ^ (((nl>>2)&7)<<2))];
    ushort4 bv; bv.x=f2b(v.x); bv.y=f2b(v.y); bv.z=f2b(v.z); bv.w=f2b(v.w);
    *(ushort4*)(xtp + (size_t)nl*CH + c4) = bv;
  }
}

// ---------------- kernel 2: Gram partials, 64x64 symmetric tiles (10 of 16), KC=4
// grid 640 = 16b x 4kc x 10 tiles, XCD-swizzled (640 = 8*80, 2 batches/XCD).
// Block 256 thr = 4 waves (2x2), wave tile 32x32, BK=64, K=1024 per block.
// Compact Sp layout: [b][kc][tile][64][64] f32.
__global__ __launch_bounds__(256) void k_gram(const u16* __restrict__ xb, float* __restrict__ Sp) {
  __shared__ u16 As[64*64];   // 8 KB
  __shared__ u16 Bs[64*64];   // 8 KB
  const int TIa[10] = {0,0,0,0,1,1,1,2,2,3};
  const int TJa[10] = {0,1,2,3,1,2,3,2,3,3};
  const int L = blockIdx.x;
  const int wk = (L & 7) * 80 + (L >> 3);   // bijective: 640 = 8*80
  const int b = wk / 40;
  const int rem = wk % 40;
  const int kc = rem / 10;
  const int tile = rem % 10;
  const int ti = TIa[tile], tj = TJa[tile];
  const int m_base = ti*64, n_base = tj*64;
  const bool diag = (ti == tj);
  const int t = threadIdx.x, wv = t >> 6, l = t & 63;
  const int wr = wv >> 1, wc = wv & 1;
  const int lr = l & 15, lkb = l >> 4;      // fragment row lane, k sub-block
  const int sr8 = l >> 3, ss = l & 7;       // staging: row-within-8, 16B slot
  const u16* xa = xb + (size_t)b*CH*NSP;
  const int kbeg = kc * (NSP/KC);
  f32x4 acc[2][2];
  #pragma unroll
  for (int i = 0; i < 2; ++i)
    #pragma unroll
    for (int j = 0; j < 2; ++j) acc[i][j] = (f32x4){0.f,0.f,0.f,0.f};

  for (int kk = 0; kk < 16; ++kk) {
    const int kpos = kbeg + kk*64;
    // stage A (64 rows x 64 k = 8 KB): 8 x 1KB groups, 2 per wave
    #pragma unroll
    for (int j = 0; j < 2; ++j) {
      const int g = wv*2 + j;               // 0..7
      const int r = g*8 + sr8;              // 0..63
      async16(&As[g*512], xa + (size_t)(m_base + r)*NSP + kpos + ((ss ^ (r & 7)) * 8));
    }
    if (!diag) {
      #pragma unroll
      for (int j = 0; j < 2; ++j) {
        const int g = wv*2 + j;
        const int r = g*8 + sr8;
        async16(&Bs[g*512], xa + (size_t)(n_base + r)*NSP + kpos + ((ss ^ (r & 7)) * 8));
      }
    }
    __syncthreads();
    const u16* bsrc = diag ? As : Bs;
    #pragma unroll
    for (int ks = 0; ks < 2; ++ks) {
      bf16x8 A[2], Bf[2];
      #pragma unroll
      for (int mt = 0; mt < 2; ++mt) {
        const int ra = wr*32 + mt*16 + lr;
        A[mt] = *(const bf16x8*)(As + ra*64 + (((ks*4 + lkb) ^ (ra & 7)) * 8));
      }
      #pragma unroll
      for (int nt = 0; nt < 2; ++nt) {
        const int rb = wc*32 + nt*16 + lr;
        Bf[nt] = *(const bf16x8*)(bsrc + rb*64 + (((ks*4 + lkb) ^ (rb & 7)) * 8));
      }
      #pragma unroll
      for (int mt = 0; mt < 2; ++mt)
        #pragma unroll
        for (int nt = 0; nt < 2; ++nt)
          acc[mt][nt] = __builtin_amdgcn_mfma_f32_16x16x32_bf16(A[mt], Bf[nt], acc[mt][nt], 0, 0, 0);
    }
    __syncthreads();
  }
  float* Sb = Sp + (size_t)((b*KC + kc)*10 + tile)*4096;
  const int r0 = (l >> 4) * 4;
  #pragma unroll
  for (int mt = 0; mt < 2; ++mt)
    #pragma unroll
    for (int nt = 0; nt < 2; ++nt)
      #pragma unroll
      for (int rr = 0; rr < 4; ++rr) {
        const int lm = wr*32 + mt*16 + r0 + rr;
        const int lc = wc*32 + nt*16 + lr;
        Sb[lm*64 + lc] = acc[mt][nt][rr];
      }
}

// ---------------- fused: reduce Sp tiles -> S (with symmetric mirror) + per-batch vectors
// grid (11, BATCH): x<10 tile-reduce role; x==10 vec role.
__global__ __launch_bounds__(256) void k_redvec(const float* __restrict__ Sp,
    const float* __restrict__ psum, const float* __restrict__ E,
    const float* __restrict__ KT, const float* __restrict__ q,
    float* __restrict__ S, float* __restrict__ KS, float* __restrict__ Es,
    float* __restrict__ qs) {
  __shared__ float tl[64*65 + 8];
  const int b = blockIdx.y, xx = blockIdx.x, t = threadIdx.x;
  if (xx < 10) {
    const int TIa[10] = {0,0,0,0,1,1,1,2,2,3};
    const int TJa[10] = {0,1,2,3,1,2,3,2,3,3};
    const int ti = TIa[xx], tj = TJa[xx];
    const int row0 = ti*64, col0 = tj*64;
    float* Sb = S + (size_t)b*CH*CH;
    float4 sum[4];
    #pragma unroll
    for (int k = 0; k < 4; ++k) {
      const int slot = t + k*256;
      const int r = slot >> 4, c4 = (slot & 15) * 4;
      float4 s = {0.f,0.f,0.f,0.f};
      #pragma unroll
      for (int kc = 0; kc < KC; ++kc) {
        const float* p = Sp + (size_t)((b*KC + kc)*10 + xx)*4096;
        float4 v = *(const float4*)(p + r*64 + c4);
        s.x += v.x; s.y += v.y; s.z += v.z; s.w += v.w;
      }
      sum[k] = s;
      *(float4*)(Sb + (size_t)(row0 + r)*CH + col0 + c4) = s;
    }
    if (ti != tj) {                            // mirror to lower triangle
      #pragma unroll
      for (int k = 0; k < 4; ++k) {
        const int slot = t + k*256;
        const int r = slot >> 4, c4 = (slot & 15) * 4;
        tl[r*65 + c4+0] = sum[k].x; tl[r*65 + c4+1] = sum[k].y;
        tl[r*65 + c4+2] = sum[k].z; tl[r*65 + c4+3] = sum[k].w;
      }
      __syncthreads();
      #pragma unroll
      for (int k = 0; k < 4; ++k) {
        const int slot = t + k*256;
        const int r = slot >> 4, c4 = (slot & 15) * 4;
        float4 v = { tl[(c4+0)*65 + r], tl[(c4+1)*65 + r],
                     tl[(c4+2)*65 + r], tl[(c4+3)*65 + r] };
        *(float4*)(Sb + (size_t)(col0 + r)*CH + row0 + c4) = v;
      }
    }
  } else {
    // vec role: s from psum; KS = KT^T s; Es = E s; qs = q.s
    float s = 0.f;
    for (int nb = 0; nb < 64; ++nb) s += psum[((size_t)b*64 + nb)*CH + t];
    tl[t] = s;
    __syncthreads();
    float ks = 0.f;
    for (int a = 0; a < CH; ++a) ks += KT[(size_t)a*CH + t] * tl[a];
    KS[(size_t)b*CH + t] = ks;
    float es = 0.f;
    for (int c = 0; c < CH; ++c) es += E[(size_t)t*CH + c] * tl[c];
    Es[(size_t)b*CH + t] = es;
    float p = q[t] * tl[t];
    #pragma unroll
    for (int o = 1; o < 64; o <<= 1) p += __shfl_xor(p, o, 64);
    if ((t & 63) == 0) tl[4160 + (t >> 6)] = p;
    __syncthreads();
    if (t == 0) qs[b] = tl[4160] + tl[4161] + tl[4162] + tl[4163];
  }
}

// ---------------- k_RP: fused R = E·S (LDS-resident) then P = (inv/N)(R·KT + rank1s) + I
__global__ __launch_bounds__(256) void k_RP(const float* __restrict__ S,
    const float* __restrict__ E, const float* __restrict__ KT,
    const float* __restrict__ q, const float* __restrict__ KS,
    const float* __restrict__ Es, const float* __restrict__ qs,
    const float* __restrict__ wg, const float* __restrict__ tphi,
    const float* __restrict__ inv, const float* __restrict__ dconst,
    const float* __restrict__ tb, u16* __restrict__ Pb, float* __restrict__ dv) {
  __shared__ float lEt[2048];
  __shared__ float lRt[2048];
  __shared__ float red[32];
  const int b = blockIdx.y, o0 = blockIdx.x*8, t = threadIdx.x;
  #pragma unroll
  for (int k = 0; k < 8; ++k) { int idx = k*256 + t;
    lEt[idx] = E[(size_t)(o0 + (idx & 7))*CH + (idx >> 3)]; }
  __syncthreads();
  const float* Sb = S + (size_t)b*CH*CH;
  float acc[8] = {0.f};
  for (int c = 0; c < CH; ++c) {
    float sv = Sb[(size_t)c*CH + t];
    #pragma unroll
    for (int r = 0; r < 8; ++r) acc[r] += lEt[c*8 + r] * sv;
  }
  #pragma unroll
  for (int r = 0; r < 8; ++r) lRt[t*8 + r] = acc[r];
  const float qt = q[t];
  #pragma unroll
  for (int r = 0; r < 8; ++r) {
    float p = acc[r] * qt;
    #pragma unroll
    for (int o = 1; o < 64; o <<= 1) p += __shfl_xor(p, o, 64);
    if ((t & 63) == 0) red[r*4 + (t >> 6)] = p;
  }
  __syncthreads();
  float acc2[8] = {0.f};
  for (int a = 0; a < CH; ++a) {
    float kv = KT[(size_t)a*CH + t];
    #pragma unroll
    for (int r = 0; r < 8; ++r) acc2[r] += lRt[a*8 + r] * kv;
  }
  const float ksv = KS[(size_t)b*CH + t], tpv = tphi[t];
  u16* Pbb = Pb + (size_t)b*CH*CH;
  #pragma unroll
  for (int r = 0; r < 8; ++r) {
    int o = o0 + r;
    float val = (acc2[r] + wg[o]*ksv + (Es[(size_t)b*CH + o] + (float)NSP*wg[o])*tpv)
                * inv[o] * (1.f/(float)NSP);
    if (o == t) val += 1.f;      // fold residual: P + I
    Pbb[(size_t)o*CH + t] = f2b(val);
  }
  if (t < 8) {
    int o = o0 + t;
    float iv = inv[o], wgo = wg[o], tb0 = tb[0];
    float rq = red[t*4] + red[t*4+1] + red[t*4+2] + red[t*4+3];
    float t2 = rq + wgo*qs[b] + Es[(size_t)b*CH + o]*tb0;
    dv[(size_t)b*CH + o] = iv*(t2*(1.f/(float)NSP) + wgo*tb0) + dconst[o];
  }
}

// ---------------- apply: out = (P+I) X + d 1^T  (LDS-staged B, coalesced f32 epilogue)
// grid (NSP/64, BATCH), block 512 = 8 waves, wave tile 32 rows x 64 cols
__global__ __launch_bounds__(512, 4) void k_apply(const u16* __restrict__ Pb,
    const u16* __restrict__ xt, const float* __restrict__ dv,
    float* __restrict__ out) {
  __shared__ union {
    u16   bx[64*256];        // 32 KB bf16 B-tile (XOR-swizzled 16B slots)
    float fe[8][16][68];     // 34 KB per-wave f32 epilogue buffers (stride 68)
  } sm;
  const int b = blockIdx.y, n0 = blockIdx.x*64;
  const int t = threadIdx.x, w = t >> 6, l = t & 63;
  {
    const u16* src = xt + ((size_t)b*NSP + n0)*CH;
    const int r = t >> 3, sbase = t & 7;
    #pragma unroll
    for (int it = 0; it < 4; ++it) {
      int slot = sbase + it*8;         // 0..31 (16B slots within 512B row)
      bf16x8 v = *(const bf16x8*)(src + (size_t)r*CH + slot*8);
      *(bf16x8*)(sm.bx + r*256 + ((slot ^ (r & 7)) * 8)) = v;
    }
  }
  __syncthreads();
  const int m0 = w*32;
  const int lr = l & 15, lkb = l >> 4;   // k sub-block 0..3 (8 elems each)
  const int sw = lr & 7;
  const u16* Pp = Pb + (size_t)b*CH*CH;
  f32x4 acc[2][4];
  #pragma unroll
  for (int i = 0; i < 2; ++i)
    #pragma unroll
    for (int j = 0; j < 4; ++j) acc[i][j] = (f32x4){0.f,0.f,0.f,0.f};
  #pragma unroll
  for (int kk = 0; kk < 8; ++kk) {
    bf16x8 A[2], Bf[4];
    #pragma unroll
    for (int mt = 0; mt < 2; ++mt)
      A[mt] = *(const bf16x8*)(Pp + (size_t)(m0 + mt*16 + lr)*CH + kk*32 + lkb*8);
    #pragma unroll
    for (int nt = 0; nt < 4; ++nt) {
      int slot = kk*4 + lkb;
      Bf[nt] = *(const bf16x8*)(sm.bx + (nt*16 + lr)*256 + ((slot ^ sw) * 8));
    }
    #pragma unroll
    for (int mt = 0; mt < 2; ++mt)
      #pragma unroll
      for (int nt = 0; nt < 4; ++nt)
        acc[mt][nt] = __builtin_amdgcn_mfma_f32_16x16x32_bf16(A[mt], Bf[nt], acc[mt][nt], 0, 0, 0);
  }
  __syncthreads();                     // B-tile dead; reuse LDS for epilogue
  float* ob = out + (size_t)b*CH*NSP;
  const int r0 = (l >> 4) * 4;
  #pragma unroll
  for (int mt = 0; mt < 2; ++mt) {
    #pragma unroll
    for (int rr = 0; rr < 4; ++rr) {
      float dval = dv[(size_t)b*CH + m0 + mt*16 + r0 + rr];
      #pragma unroll
      for (int nt = 0; nt < 4; ++nt)
        sm.fe[w][r0 + rr][nt*16 + lr] = acc[mt][nt][rr] + dval;
    }
    #pragma unroll
    for (int i = 0; i < 4; ++i) {
      int s = l + 64*i;
      int rrow = s >> 4, c4 = (s & 15) * 4;
      float4 v = *(const float4*)&sm.fe[w][rrow][c4];
      *(float4*)&ob[(size_t)(m0 + mt*16 + rrow)*NSP + n0 + c4] = v;
    }
  }
}

// ---------------- workspace layout (bytes)
static constexpr size_t XT_OFF = 0;              // bf16 [16][4096][256]  33,554,432
static constexpr size_t S_OFF  = 33554432;       // f32  [16][256][256]    4,194,304
static constexpr size_t PB_OFF = 37748736;       // bf16 [16][256][256]    2,097,152
static constexpr size_t PS_OFF = 39845888;       // f32  [16][64][256]     1,048,576
static constexpr size_t E_OFF  = 40894464;       // f32  [256][256]          262,144
static constexpr size_t KT_OFF = 41156608;       // f32  [256][256]          262,144
static constexpr size_t WG_OFF = 41418752;       // f32 [256] (1K pad each follows)
static constexpr size_t TP_OFF = 41419776;
static constexpr size_t QV_OFF = 41420800;
static constexpr size_t IV_OFF = 41421824;
static constexpr size_t DC_OFF = 41422848;
static constexpr size_t TB_OFF = 41423872;
static constexpr size_t KS_OFF = 41424896;       // f32 [16][256] 16,384
static constexpr size_t ES_OFF = 41441280;       // f32 [16][256] 16,384
static constexpr size_t QS_OFF = 41457664;       // f32 [16] (1K pad)
static constexpr size_t DV_OFF = 41458688;       // f32 [16][256] 16,384

extern "C" void kernel_launch(void* const* d_in, const int* in_sizes, int n_in,
                              void* d_out, int out_size, void* d_ws, size_t ws_size,
                              hipStream_t stream) {
  const float* x       = (const float*)d_in[0];
  const float* g_w     = (const float*)d_in[1];
  const float* g_b     = (const float*)d_in[2];
  const float* theta_w = (const float*)d_in[3];
  const float* theta_b = (const float*)d_in[4];
  const float* phi_w   = (const float*)d_in[5];
  const float* phi_b   = (const float*)d_in[6];
  const float* w_w     = (const float*)d_in[7];
  const float* w_b     = (const float*)d_in[8];
  const float* bn_g    = (const float*)d_in[9];
  const float* bn_b    = (const float*)d_in[10];
  const float* bn_m    = (const float*)d_in[11];
  const float* bn_v    = (const float*)d_in[12];
  float* out = (float*)d_out;
  char* ws = (char*)d_ws;
  u16*   XT = (u16*)(ws + XT_OFF);
  float* S  = (float*)(ws + S_OFF);
  u16*   Pb = (u16*)(ws + PB_OFF);
  float* PS = (float*)(ws + PS_OFF);
  float* E  = (float*)(ws + E_OFF);
  float* KT = (float*)(ws + KT_OFF);
  float* WG = (float*)(ws + WG_OFF);
  float* TP = (float*)(ws + TP_OFF);
  float* QV = (float*)(ws + QV_OFF);
  float* IV = (float*)(ws + IV_OFF);
  float* DC = (float*)(ws + DC_OFF);
  float* TB = (float*)(ws + TB_OFF);
  float* KS = (float*)(ws + KS_OFF);
  float* ES = (float*)(ws + ES_OFF);
  float* QS = (float*)(ws + QS_OFF);
  float* DV = (float*)(ws + DV_OFF);
  // d_out scratch: Xb bf16 [0, 33.5MB); compact Sp [33.5MB, +10.5MB). Dead before k_apply.
  u16*   Xb = (u16*)d_out;
  float* Sp = (float*)((char*)d_out + 33554432);

  k_const <<<dim3(65),                    256, 0, stream>>>(w_w, g_w, g_b, theta_w, theta_b,
                                                            phi_w, phi_b, w_b, bn_g, bn_b, bn_m, bn_v,
                                                            E, KT, WG, TP, QV, IV, DC, TB);
  k_prep  <<<dim3(NSP/64, CH/64, BATCH),  256, 0, stream>>>(x, Xb, XT, PS);
  k_gram  <<<dim3(640),                   256, 0, stream>>>(Xb, Sp);
  k_redvec<<<dim3(11, BATCH),             256, 0, stream>>>(Sp, PS, E, KT, QV, S, KS, ES, QS);
  k_RP    <<<dim3(32, BATCH),             256, 0, stream>>>(S, E, KT, QV, KS, ES, QS, WG, TP, IV, DC, TB, Pb, DV);
  k_apply <<<dim3(NSP/64, BATCH),         512, 0, stream>>>(Pb, XT, DV, out);
}

// Round 9
// 121.112 us; speedup vs baseline: 2.8174x; 1.0513x over previous
//
#include <hip/hip_runtime.h>
#include <stdint.h>

#define BATCH 16
#define CH    256
#define CI    128
#define NSP   4096
#define KC    4          // K-split chunks for the Gram GEMM
#define EPSV  1e-5f

typedef unsigned short u16;
typedef __attribute__((ext_vector_type(4))) float f32x4;
typedef __attribute__((ext_vector_type(8))) short bf16x8;

__device__ __forceinline__ u16 f2b(float f) {
  uint32_t u = __float_as_uint(f);
  uint32_t r = u + 0x7FFFu + ((u >> 16) & 1u);   // round-to-nearest-even
  return (u16)(r >> 16);
}

__device__ __forceinline__ void async16(void* lds, const void* g) {
  __builtin_amdgcn_global_load_lds(
      (const __attribute__((address_space(1))) unsigned int*)g,
      (__attribute__((address_space(3))) unsigned int*)lds, 16, 0, 0);
}

// ---------------- k_prep: bf16 convert (row-major + transposed) + row-sum partials.
// grid (64, 4, 17): z<16 = batch slices (R7's proven streaming+transpose body);
// z==16 = merged k_const roles (E, KT, per-channel vectors) — byte-identical role code.
__global__ __launch_bounds__(256) void k_prep(const float* __restrict__ x,
    u16* __restrict__ xb, u16* __restrict__ xt, float* __restrict__ psum,
    const float* __restrict__ w_w, const float* __restrict__ g_w,
    const float* __restrict__ g_b, const float* __restrict__ theta_w,
    const float* __restrict__ theta_b, const float* __restrict__ phi_w,
    const float* __restrict__ phi_b, const float* __restrict__ w_b,
    const float* __restrict__ bn_g, const float* __restrict__ bn_b,
    const float* __restrict__ bn_m, const float* __restrict__ bn_v,
    float* __restrict__ E, float* __restrict__ KT, float* __restrict__ wg,
    float* __restrict__ tphi, float* __restrict__ q, float* __restrict__ inv,
    float* __restrict__ dconst, float* __restrict__ tb) {
  __shared__ float tile[64*64];
  const int t = threadIdx.x;
  if (blockIdx.z == BATCH) {                 // ---- const role (R7 k_const body)
    float* lbuf = tile;                      // needs only 1024 floats
    const int id = blockIdx.y*64 + blockIdx.x;
    if (id < 32) {                           // E rows o0..o0+7
      const int o0 = id*8;
      #pragma unroll
      for (int k = 0; k < 4; ++k) { int idx = k*256 + t;
        lbuf[idx] = w_w[(size_t)(o0 + (idx & 7))*CI + (idx >> 3)]; }
      __syncthreads();
      float acc[8] = {0.f};
      for (int j = 0; j < CI; ++j) {
        float gv = g_w[(size_t)j*CH + t];
        #pragma unroll
        for (int r = 0; r < 8; ++r) acc[r] += lbuf[j*8 + r] * gv;
      }
      #pragma unroll
      for (int r = 0; r < 8; ++r) E[(size_t)(o0 + r)*CH + t] = acc[r];
    } else if (id < 64) {                    // KT rows a0..a0+7
      const int a0 = (id - 32)*8;
      #pragma unroll
      for (int k = 0; k < 4; ++k) { int idx = k*256 + t;
        lbuf[idx] = phi_w[(size_t)(idx >> 3)*CH + a0 + (idx & 7)]; }
      __syncthreads();
      float acc[8] = {0.f};
      for (int i = 0; i < CI; ++i) {
        float tv = theta_w[(size_t)i*CH + t];
        #pragma unroll
        for (int u = 0; u < 8; ++u) acc[u] += lbuf[i*8 + u] * tv;
      }
      #pragma unroll
      for (int u = 0; u < 8; ++u) KT[(size_t)(a0 + u)*CH + t] = acc[u];
    } else if (id == 64) {                   // vectors
      float iv = bn_g[t] * rsqrtf(bn_v[t] + EPSV);
      inv[t] = iv;
      dconst[t] = iv*w_b[t] + bn_b[t] - bn_m[t]*iv;
      float a = 0.f;
      for (int j = 0; j < CI; ++j) a += w_w[(size_t)t*CI + j] * g_b[j];
      wg[t] = a;
      float tp = 0.f, qq = 0.f;
      for (int i = 0; i < CI; ++i) {
        tp += theta_w[(size_t)i*CH + t] * phi_b[i];
        qq += phi_w[(size_t)i*CH + t] * theta_b[i];
      }
      tphi[t] = tp; q[t] = qq;
      lbuf[t] = (t < CI) ? theta_b[t]*phi_b[t] : 0.f;
      __syncthreads();
      for (int s2 = 128; s2 > 0; s2 >>= 1) { if (t < s2) lbuf[t] += lbuf[t + s2]; __syncthreads(); }
      if (t == 0) tb[0] = lbuf[0];
    }
    return;
  }
  // ---- streaming role (R7 body, unchanged)
  const int b = blockIdx.z, c0 = blockIdx.y*64, n0 = blockIdx.x*64;
  const int lane16 = t & 15;
  const int grp = t >> 4;              // 0..15
  const float* xp = x + ((size_t)b*CH + c0)*NSP + n0;
  u16* xbp = xb + ((size_t)b*CH + c0)*NSP + n0;
  #pragma unroll
  for (int p = 0; p < 4; ++p) {
    int cl = grp + p*16;               // row within tile, 0..63
    int nl = lane16*4;
    float4 v = *(const float4*)(xp + (size_t)cl*NSP + nl);
    float ps = v.x + v.y + v.z + v.w;
    #pragma unroll
    for (int o = 1; o < 16; o <<= 1) ps += __shfl_xor(ps, o, 64);
    if (lane16 == 0) psum[((size_t)b*64 + blockIdx.x)*CH + c0 + cl] = ps;
    ushort4 bv; bv.x=f2b(v.x); bv.y=f2b(v.y); bv.z=f2b(v.z); bv.w=f2b(v.w);
    *(ushort4*)(xbp + (size_t)cl*NSP + nl) = bv;
    float vv[4] = {v.x, v.y, v.z, v.w};
    #pragma unroll
    for (int j = 0; j < 4; ++j) {
      int n = nl + j;
      tile[n*64 + (cl ^ (((n>>2)&7)<<2))] = vv[j];
    }
  }
  __syncthreads();
  u16* xtp = xt + ((size_t)b*NSP + n0)*CH + c0;
  #pragma unroll
  for (int q2 = 0; q2 < 4; ++q2) {
    int nl = grp + q2*16;
    int c4 = lane16*4;
    float4 v = *(const float4*)&tile[nl*64 + (c4 ^ (((nl>>2)&7)<<2))];
    ushort4 bv; bv.x=f2b(v.x); bv.y=f2b(v.y); bv.z=f2b(v.z); bv.w=f2b(v.w);
    *(ushort4*)(xtp + (size_t)nl*CH + c4) = bv;
  }
}

// ---------------- kernel 2: Gram partials, 64x64 symmetric tiles (10 of 16), KC=4
__global__ __launch_bounds__(256) void k_gram(const u16* __restrict__ xb, float* __restrict__ Sp) {
  __shared__ u16 As[64*64];   // 8 KB
  __shared__ u16 Bs[64*64];   // 8 KB
  const int TIa[10] = {0,0,0,0,1,1,1,2,2,3};
  const int TJa[10] = {0,1,2,3,1,2,3,2,3,3};
  const int L = blockIdx.x;
  const int wk = (L & 7) * 80 + (L >> 3);   // bijective: 640 = 8*80
  const int b = wk / 40;
  const int rem = wk % 40;
  const int kc = rem / 10;
  const int tile = rem % 10;
  const int ti = TIa[tile], tj = TJa[tile];
  const int m_base = ti*64, n_base = tj*64;
  const bool diag = (ti == tj);
  const int t = threadIdx.x, wv = t >> 6, l = t & 63;
  const int wr = wv >> 1, wc = wv & 1;
  const int lr = l & 15, lkb = l >> 4;      // fragment row lane, k sub-block
  const int sr8 = l >> 3, ss = l & 7;       // staging: row-within-8, 16B slot
  const u16* xa = xb + (size_t)b*CH*NSP;
  const int kbeg = kc * (NSP/KC);
  f32x4 acc[2][2];
  #pragma unroll
  for (int i = 0; i < 2; ++i)
    #pragma unroll
    for (int j = 0; j < 2; ++j) acc[i][j] = (f32x4){0.f,0.f,0.f,0.f};

  for (int kk = 0; kk < 16; ++kk) {
    const int kpos = kbeg + kk*64;
    #pragma unroll
    for (int j = 0; j < 2; ++j) {
      const int g = wv*2 + j;               // 0..7
      const int r = g*8 + sr8;              // 0..63
      async16(&As[g*512], xa + (size_t)(m_base + r)*NSP + kpos + ((ss ^ (r & 7)) * 8));
    }
    if (!diag) {
      #pragma unroll
      for (int j = 0; j < 2; ++j) {
        const int g = wv*2 + j;
        const int r = g*8 + sr8;
        async16(&Bs[g*512], xa + (size_t)(n_base + r)*NSP + kpos + ((ss ^ (r & 7)) * 8));
      }
    }
    __syncthreads();
    const u16* bsrc = diag ? As : Bs;
    #pragma unroll
    for (int ks = 0; ks < 2; ++ks) {
      bf16x8 A[2], Bf[2];
      #pragma unroll
      for (int mt = 0; mt < 2; ++mt) {
        const int ra = wr*32 + mt*16 + lr;
        A[mt] = *(const bf16x8*)(As + ra*64 + (((ks*4 + lkb) ^ (ra & 7)) * 8));
      }
      #pragma unroll
      for (int nt = 0; nt < 2; ++nt) {
        const int rb = wc*32 + nt*16 + lr;
        Bf[nt] = *(const bf16x8*)(bsrc + rb*64 + (((ks*4 + lkb) ^ (rb & 7)) * 8));
      }
      #pragma unroll
      for (int mt = 0; mt < 2; ++mt)
        #pragma unroll
        for (int nt = 0; nt < 2; ++nt)
          acc[mt][nt] = __builtin_amdgcn_mfma_f32_16x16x32_bf16(A[mt], Bf[nt], acc[mt][nt], 0, 0, 0);
    }
    __syncthreads();
  }
  float* Sb = Sp + (size_t)((b*KC + kc)*10 + tile)*4096;
  const int r0 = (l >> 4) * 4;
  #pragma unroll
  for (int mt = 0; mt < 2; ++mt)
    #pragma unroll
    for (int nt = 0; nt < 2; ++nt)
      #pragma unroll
      for (int rr = 0; rr < 4; ++rr) {
        const int lm = wr*32 + mt*16 + r0 + rr;
        const int lc = wc*32 + nt*16 + lr;
        Sb[lm*64 + lc] = acc[mt][nt][rr];
      }
}

// ---------------- fused: reduce Sp tiles -> S (with symmetric mirror) + per-batch vectors
__global__ __launch_bounds__(256) void k_redvec(const float* __restrict__ Sp,
    const float* __restrict__ psum, const float* __restrict__ E,
    const float* __restrict__ KT, const float* __restrict__ q,
    float* __restrict__ S, float* __restrict__ KS, float* __restrict__ Es,
    float* __restrict__ qs) {
  __shared__ float tl[64*65 + 8];
  const int b = blockIdx.y, xx = blockIdx.x, t = threadIdx.x;
  if (xx < 10) {
    const int TIa[10] = {0,0,0,0,1,1,1,2,2,3};
    const int TJa[10] = {0,1,2,3,1,2,3,2,3,3};
    const int ti = TIa[xx], tj = TJa[xx];
    const int row0 = ti*64, col0 = tj*64;
    float* Sb = S + (size_t)b*CH*CH;
    float4 sum[4];
    #pragma unroll
    for (int k = 0; k < 4; ++k) {
      const int slot = t + k*256;
      const int r = slot >> 4, c4 = (slot & 15) * 4;
      float4 s = {0.f,0.f,0.f,0.f};
      #pragma unroll
      for (int kc = 0; kc < KC; ++kc) {
        const float* p = Sp + (size_t)((b*KC + kc)*10 + xx)*4096;
        float4 v = *(const float4*)(p + r*64 + c4);
        s.x += v.x; s.y += v.y; s.z += v.z; s.w += v.w;
      }
      sum[k] = s;
      *(float4*)(Sb + (size_t)(row0 + r)*CH + col0 + c4) = s;
    }
    if (ti != tj) {                            // mirror to lower triangle
      #pragma unroll
      for (int k = 0; k < 4; ++k) {
        const int slot = t + k*256;
        const int r = slot >> 4, c4 = (slot & 15) * 4;
        tl[r*65 + c4+0] = sum[k].x; tl[r*65 + c4+1] = sum[k].y;
        tl[r*65 + c4+2] = sum[k].z; tl[r*65 + c4+3] = sum[k].w;
      }
      __syncthreads();
      #pragma unroll
      for (int k = 0; k < 4; ++k) {
        const int slot = t + k*256;
        const int r = slot >> 4, c4 = (slot & 15) * 4;
        float4 v = { tl[(c4+0)*65 + r], tl[(c4+1)*65 + r],
                     tl[(c4+2)*65 + r], tl[(c4+3)*65 + r] };
        *(float4*)(Sb + (size_t)(col0 + r)*CH + row0 + c4) = v;
      }
    }
  } else {
    float s = 0.f;
    for (int nb = 0; nb < 64; ++nb) s += psum[((size_t)b*64 + nb)*CH + t];
    tl[t] = s;
    __syncthreads();
    float ks = 0.f;
    for (int a = 0; a < CH; ++a) ks += KT[(size_t)a*CH + t] * tl[a];
    KS[(size_t)b*CH + t] = ks;
    float es = 0.f;
    for (int c = 0; c < CH; ++c) es += E[(size_t)t*CH + c] * tl[c];
    Es[(size_t)b*CH + t] = es;
    float p = q[t] * tl[t];
    #pragma unroll
    for (int o = 1; o < 64; o <<= 1) p += __shfl_xor(p, o, 64);
    if ((t & 63) == 0) tl[4160 + (t >> 6)] = p;
    __syncthreads();
    if (t == 0) qs[b] = tl[4160] + tl[4161] + tl[4162] + tl[4163];
  }
}

// ---------------- k_RP: fused R = E·S (LDS-resident) then P = (inv/N)(R·KT + rank1s) + I
__global__ __launch_bounds__(256) void k_RP(const float* __restrict__ S,
    const float* __restrict__ E, const float* __restrict__ KT,
    const float* __restrict__ q, const float* __restrict__ KS,
    const float* __restrict__ Es, const float* __restrict__ qs,
    const float* __restrict__ wg, const float* __restrict__ tphi,
    const float* __restrict__ inv, const float* __restrict__ dconst,
    const float* __restrict__ tb, u16* __restrict__ Pb, float* __restrict__ dv) {
  __shared__ float lEt[2048];
  __shared__ float lRt[2048];
  __shared__ float red[32];
  const int b = blockIdx.y, o0 = blockIdx.x*8, t = threadIdx.x;
  #pragma unroll
  for (int k = 0; k < 8; ++k) { int idx = k*256 + t;
    lEt[idx] = E[(size_t)(o0 + (idx & 7))*CH + (idx >> 3)]; }
  __syncthreads();
  const float* Sb = S + (size_t)b*CH*CH;
  float acc[8] = {0.f};
  for (int c = 0; c < CH; ++c) {
    float sv = Sb[(size_t)c*CH + t];
    #pragma unroll
    for (int r = 0; r < 8; ++r) acc[r] += lEt[c*8 + r] * sv;
  }
  #pragma unroll
  for (int r = 0; r < 8; ++r) lRt[t*8 + r] = acc[r];
  const float qt = q[t];
  #pragma unroll
  for (int r = 0; r < 8; ++r) {
    float p = acc[r] * qt;
    #pragma unroll
    for (int o = 1; o < 64; o <<= 1) p += __shfl_xor(p, o, 64);
    if ((t & 63) == 0) red[r*4 + (t >> 6)] = p;
  }
  __syncthreads();
  float acc2[8] = {0.f};
  for (int a = 0; a < CH; ++a) {
    float kv = KT[(size_t)a*CH + t];
    #pragma unroll
    for (int r = 0; r < 8; ++r) acc2[r] += lRt[a*8 + r] * kv;
  }
  const float ksv = KS[(size_t)b*CH + t], tpv = tphi[t];
  u16* Pbb = Pb + (size_t)b*CH*CH;
  #pragma unroll
  for (int r = 0; r < 8; ++r) {
    int o = o0 + r;
    float val = (acc2[r] + wg[o]*ksv + (Es[(size_t)b*CH + o] + (float)NSP*wg[o])*tpv)
                * inv[o] * (1.f/(float)NSP);
    if (o == t) val += 1.f;      // fold residual: P + I
    Pbb[(size_t)o*CH + t] = f2b(val);
  }
  if (t < 8) {
    int o = o0 + t;
    float iv = inv[o], wgo = wg[o], tb0 = tb[0];
    float rq = red[t*4] + red[t*4+1] + red[t*4+2] + red[t*4+3];
    float t2 = rq + wgo*qs[b] + Es[(size_t)b*CH + o]*tb0;
    dv[(size_t)b*CH + o] = iv*(t2*(1.f/(float)NSP) + wgo*tb0) + dconst[o];
  }
}

// ---------------- apply: out = (P+I) X + d 1^T  (LDS-staged B, coalesced f32 epilogue)
// grid (NSP/64, BATCH), block 512 = 8 waves, wave tile 32 rows x 64 cols
__global__ __launch_bounds__(512, 4) void k_apply(const u16* __restrict__ Pb,
    const u16* __restrict__ xt, const float* __restrict__ dv,
    float* __restrict__ out) {
  __shared__ union {
    u16   bx[64*256];        // 32 KB bf16 B-tile (XOR-swizzled 16B slots)
    float fe[8][16][68];     // 34 KB per-wave f32 epilogue buffers (stride 68)
  } sm;
  const int b = blockIdx.y, n0 = blockIdx.x*64;
  const int t = threadIdx.x, w = t >> 6, l = t & 63;
  {
    const u16* src = xt + ((size_t)b*NSP + n0)*CH;
    const int r = t >> 3, sbase = t & 7;
    #pragma unroll
    for (int it = 0; it < 4; ++it) {
      int slot = sbase + it*8;         // 0..31 (16B slots within 512B row)
      bf16x8 v = *(const bf16x8*)(src + (size_t)r*CH + slot*8);
      *(bf16x8*)(sm.bx + r*256 + ((slot ^ (r & 7)) * 8)) = v;
    }
  }
  __syncthreads();
  const int m0 = w*32;
  const int lr = l & 15, lkb = l >> 4;   // k sub-block 0..3 (8 elems each)
  const int sw = lr & 7;
  const u16* Pp = Pb + (size_t)b*CH*CH;
  f32x4 acc[2][4];
  #pragma unroll
  for (int i = 0; i < 2; ++i)
    #pragma unroll
    for (int j = 0; j < 4; ++j) acc[i][j] = (f32x4){0.f,0.f,0.f,0.f};
  #pragma unroll
  for (int kk = 0; kk < 8; ++kk) {
    bf16x8 A[2], Bf[4];
    #pragma unroll
    for (int mt = 0; mt < 2; ++mt)
      A[mt] = *(const bf16x8*)(Pp + (size_t)(m0 + mt*16 + lr)*CH + kk*32 + lkb*8);
    #pragma unroll
    for (int nt = 0; nt < 4; ++nt) {
      int slot = kk*4 + lkb;
      Bf[nt] = *(const bf16x8*)(sm.bx + (nt*16 + lr)*256 + ((slot ^ sw) * 8));
    }
    #pragma unroll
    for (int mt = 0; mt < 2; ++mt)
      #pragma unroll
      for (int nt = 0; nt < 4; ++nt)
        acc[mt][nt] = __builtin_amdgcn_mfma_f32_16x16x32_bf16(A[mt], Bf[nt], acc[mt][nt], 0, 0, 0);
  }
  __syncthreads();                     // B-tile dead; reuse LDS for epilogue
  float* ob = out + (size_t)b*CH*NSP;
  const int r0 = (l >> 4) * 4;
  #pragma unroll
  for (int mt = 0; mt < 2; ++mt) {
    #pragma unroll
    for (int rr = 0; rr < 4; ++rr) {
      float dval = dv[(size_t)b*CH + m0 + mt*16 + r0 + rr];
      #pragma unroll
      for (int nt = 0; nt < 4; ++nt)
        sm.fe[w][r0 + rr][nt*16 + lr] = acc[mt][nt][rr] + dval;
    }
    #pragma unroll
    for (int i = 0; i < 4; ++i) {
      int s = l + 64*i;
      int rrow = s >> 4, c4 = (s & 15) * 4;
      float4 v = *(const float4*)&sm.fe[w][rrow][c4];
      *(float4*)&ob[(size_t)(m0 + mt*16 + rrow)*NSP + n0 + c4] = v;
    }
  }
}

// ---------------- workspace layout (bytes)
static constexpr size_t XT_OFF = 0;              // bf16 [16][4096][256]  33,554,432
static constexpr size_t S_OFF  = 33554432;       // f32  [16][256][256]    4,194,304
static constexpr size_t PB_OFF = 37748736;       // bf16 [16][256][256]    2,097,152
static constexpr size_t PS_OFF = 39845888;       // f32  [16][64][256]     1,048,576
static constexpr size_t E_OFF  = 40894464;       // f32  [256][256]          262,144
static constexpr size_t KT_OFF = 41156608;       // f32  [256][256]          262,144
static constexpr size_t WG_OFF = 41418752;       // f32 [256] (1K pad each follows)
static constexpr size_t TP_OFF = 41419776;
static constexpr size_t QV_OFF = 41420800;
static constexpr size_t IV_OFF = 41421824;
static constexpr size_t DC_OFF = 41422848;
static constexpr size_t TB_OFF = 41423872;
static constexpr size_t KS_OFF = 41424896;       // f32 [16][256] 16,384
static constexpr size_t ES_OFF = 41441280;       // f32 [16][256] 16,384
static constexpr size_t QS_OFF = 41457664;       // f32 [16] (1K pad)
static constexpr size_t DV_OFF = 41458688;       // f32 [16][256] 16,384

extern "C" void kernel_launch(void* const* d_in, const int* in_sizes, int n_in,
                              void* d_out, int out_size, void* d_ws, size_t ws_size,
                              hipStream_t stream) {
  const float* x       = (const float*)d_in[0];
  const float* g_w     = (const float*)d_in[1];
  const float* g_b     = (const float*)d_in[2];
  const float* theta_w = (const float*)d_in[3];
  const float* theta_b = (const float*)d_in[4];
  const float* phi_w   = (const float*)d_in[5];
  const float* phi_b   = (const float*)d_in[6];
  const float* w_w     = (const float*)d_in[7];
  const float* w_b     = (const float*)d_in[8];
  const float* bn_g    = (const float*)d_in[9];
  const float* bn_b    = (const float*)d_in[10];
  const float* bn_m    = (const float*)d_in[11];
  const float* bn_v    = (const float*)d_in[12];
  float* out = (float*)d_out;
  char* ws = (char*)d_ws;
  u16*   XT = (u16*)(ws + XT_OFF);
  float* S  = (float*)(ws + S_OFF);
  u16*   Pb = (u16*)(ws + PB_OFF);
  float* PS = (float*)(ws + PS_OFF);
  float* E  = (float*)(ws + E_OFF);
  float* KT = (float*)(ws + KT_OFF);
  float* WG = (float*)(ws + WG_OFF);
  float* TP = (float*)(ws + TP_OFF);
  float* QV = (float*)(ws + QV_OFF);
  float* IV = (float*)(ws + IV_OFF);
  float* DC = (float*)(ws + DC_OFF);
  float* TB = (float*)(ws + TB_OFF);
  float* KS = (float*)(ws + KS_OFF);
  float* ES = (float*)(ws + ES_OFF);
  float* QS = (float*)(ws + QS_OFF);
  float* DV = (float*)(ws + DV_OFF);
  // d_out scratch: Xb bf16 [0, 33.5MB); compact Sp [33.5MB, +10.5MB). Dead before k_apply.
  u16*   Xb = (u16*)d_out;
  float* Sp = (float*)((char*)d_out + 33554432);

  k_prep  <<<dim3(64, 4, BATCH+1),        256, 0, stream>>>(x, Xb, XT, PS,
            w_w, g_w, g_b, theta_w, theta_b, phi_w, phi_b, w_b, bn_g, bn_b, bn_m, bn_v,
            E, KT, WG, TP, QV, IV, DC, TB);
  k_gram  <<<dim3(640),                   256, 0, stream>>>(Xb, Sp);
  k_redvec<<<dim3(11, BATCH),             256, 0, stream>>>(Sp, PS, E, KT, QV, S, KS, ES, QS);
  k_RP    <<<dim3(32, BATCH),             256, 0, stream>>>(S, E, KT, QV, KS, ES, QS, WG, TP, IV, DC, TB, Pb, DV);
  k_apply <<<dim3(NSP/64, BATCH),         512, 0, stream>>>(Pb, XT, DV, out);
}